// Round 4
// baseline (556.047 us; speedup 1.0000x reference)
//
#include <hip/hip_runtime.h>
#include <stdint.h>

#define DD 64
#define HH 128
#define WW 128
#define NVOX (DD * HH * WW)      // 1<<20
#define NWRD (NVOX / 32)         // 32768 words per mask
#define BATCH 2
#define NCLS 4
#define NMASK 12                 // 6 pred then 6 target
#define NPROB 36                 // phase*12 + m ; phase: 0=mask 1=eroded 2=background
#define NTILE 128                // (HH/8)*(DD/8) tiles of 128x8x8 voxels
#define MAXC 4096                // max components per 8192-voxel tile (checkerboard bound)
#define VNODE (NTILE * MAXC)     // virtual border node id = 524288
#define NODE_STRIDE (VNODE + 64) // ints per component-parent slot

// ---------------- global lock-free union-find (on component ids) --------
__device__ __forceinline__ int uf_find(int* P, int x) {
    while (true) {
        int p = P[x];
        if (p == x) return x;
        int gp = P[p];
        if (gp != p) P[x] = gp;   // path halving (benign race)
        x = gp;
    }
}
__device__ __forceinline__ int uf_find_ro(const int* P, int x) {
    int p;
    while ((p = P[x]) != x) x = p;
    return x;
}
__device__ __forceinline__ void uf_union(int* P, int a, int b) {
    while (true) {
        a = uf_find(P, a);
        b = uf_find(P, b);
        if (a == b) return;
        int lo = a < b ? a : b;
        int hi = a < b ? b : a;
        int old = atomicCAS(&P[hi], hi, lo);
        if (old == hi) return;
        a = lo; b = old;
    }
}

// ---------------- LDS union-find (swizzled: bank-conflict-free) ---------
#define SW(v) ((v) + ((v) >> 5))
__device__ __forceinline__ int lfind(int* lp, int x) {
    while (true) {
        int p = lp[SW(x)];
        if (p == x) return x;
        int gp = lp[SW(p)];
        if (gp != p) lp[SW(x)] = gp;
        x = gp;
    }
}
__device__ __forceinline__ void lunion(int* lp, int a, int b) {
    while (true) {
        a = lfind(lp, a);
        b = lfind(lp, b);
        if (a == b) return;
        int lo = a < b ? a : b;
        int hi = a < b ? b : a;
        int old = atomicCAS(&lp[SW(hi)], hi, lo);
        if (old == hi) return;
        a = lo; b = old;
    }
}

// word loader for problem (phase, m)
__device__ __forceinline__ uint32_t ld_word(const uint32_t* __restrict__ maskW,
                                            const uint32_t* __restrict__ erodW,
                                            int phase, int m, int w) {
    if (phase == 0) return maskW[m * NWRD + w];
    if (phase == 1) return erodW[m * NWRD + w];
    return ~maskW[m * NWRD + w];
}

// ---------------- kernels ----------------

// Build 12 bitpacked masks via ballot; zero counters.
__global__ void k_masks2(const float* __restrict__ pred, const int* __restrict__ tgt,
                         uint32_t* __restrict__ maskW, int* __restrict__ counts) {
    int tid = blockIdx.x * blockDim.x + threadIdx.x;   // 0 .. BATCH*NVOX-1
    if (tid < 64) counts[tid] = 0;
    int b = tid >> 20;
    int i = tid & (NVOX - 1);
    const float* p = pred + (size_t)b * NCLS * NVOX + i;
    float x0 = p[0], x1 = p[NVOX], x2 = p[2 * NVOX], x3 = p[3 * NVOX];
    float mx = fmaxf(fmaxf(x0, x1), fmaxf(x2, x3));
    float e0 = __expf(x0 - mx), e1 = __expf(x1 - mx), e2 = __expf(x2 - mx), e3 = __expf(x3 - mx);
    float S = e0 + e1 + e2 + e3;
    int t = tgt[(size_t)b * NVOX + i];
    int lane = threadIdx.x & 63;
    int wbase = i >> 5;
    float ev[3] = {e1, e2, e3};
    for (int c = 0; c < 3; ++c) {
        unsigned long long bal = __ballot(ev[c] / S > 0.5f);
        uint32_t* M = maskW + (size_t)(b * 3 + c) * NWRD;
        if (lane == 0)  M[wbase] = (uint32_t)bal;
        if (lane == 32) M[wbase] = (uint32_t)(bal >> 32);
        unsigned long long balT = __ballot(t == c + 1);
        uint32_t* MT = maskW + (size_t)(6 + b * 3 + c) * NWRD;
        if (lane == 0)  MT[wbase] = (uint32_t)balT;
        if (lane == 32) MT[wbase] = (uint32_t)(balT >> 32);
    }
}

// 6-conn binary erosion, border_value=0, bitwise.
__global__ void k_erode(const uint32_t* __restrict__ maskW, uint32_t* __restrict__ erodW) {
    int tid = blockIdx.x * blockDim.x + threadIdx.x;   // 0 .. 12*NWRD-1
    int m = tid / NWRD;
    int w = tid - m * NWRD;
    const uint32_t* M = maskW + (size_t)m * NWRD;
    int z = w >> 9, y = (w >> 2) & 127, q = w & 3;
    uint32_t a = M[w];
    uint32_t xl = (a << 1) | (q ? (M[w - 1] >> 31) : 0u);
    uint32_t xr = (a >> 1) | (q < 3 ? (M[w + 1] << 31) : 0u);
    uint32_t ym = (y > 0)   ? M[w - 4]   : 0u;
    uint32_t yp = (y < 127) ? M[w + 4]   : 0u;
    uint32_t zm = (z > 0)   ? M[w - 512] : 0u;
    uint32_t zp = (z < 63)  ? M[w + 512] : 0u;
    erodW[tid] = a & xl & xr & ym & yp & zm & zp;
}

// Tile-local CC (128x8x8 per block) in LDS; assigns compact component ids
// (tile*MAXC + k), writes voxel->component map C and sparse parent init.
__global__ void k_local(const uint32_t* __restrict__ maskW, const uint32_t* __restrict__ erodW,
                        int* __restrict__ Call, int* __restrict__ Pall,
                        int* __restrict__ tcount, int m0) {
    __shared__ int lp[8448];         // swizzled 8192-entry local parent
    __shared__ int lcount;
    int slot = blockIdx.y;
    int pr = m0 + slot;
    int phase = pr / 12, m = pr % 12;
    int* C = Call + (size_t)slot * NVOX;
    int* P = Pall + (size_t)slot * NODE_STRIDE;
    int tile = blockIdx.x;                         // 0..127
    int tz = tile >> 4, ty = tile & 15;
    int wl = threadIdx.x;                          // local word 0..255
    int zl = wl >> 5, yl = (wl >> 2) & 7, q = wl & 3;
    int gw = ((tz * 8 + zl) * 128 + (ty * 8 + yl)) * 4 + q;
    uint32_t a = ld_word(maskW, erodW, phase, m, gw);
    if (wl == 0) lcount = 0;
    if (blockIdx.x == 0 && wl == 0) P[VNODE] = VNODE;   // virtual border node

    // s1: x-run-head init within own word
    int lbase = wl << 5;
    {
        uint32_t wb = a;
        while (wb) {
            int p = __ffs(wb) - 1;
            uint32_t run = wb >> p;
            uint32_t inv = ~run;
            int len = inv ? (__ffs(inv) - 1) : (32 - p);
            for (int j = 0; j < len; ++j) lp[SW(lbase + p + j)] = lbase + p;
            if (p + len >= 32) break;
            wb &= ~(((1u << len) - 1u) << p);
        }
    }
    __syncthreads();

    // s2: intra-tile unions
    uint32_t aprev = q ? ld_word(maskW, erodW, phase, m, gw - 1) : 0u;
    if (a) {
        if (q && (a & 1u) && (aprev >> 31)) lunion(lp, lbase, lbase - 1);
        if (yl < 7) {
            uint32_t by = ld_word(maskW, erodW, phase, m, gw + 4);
            uint32_t ov = a & by;
            if (ov) {
                uint32_t bp = q ? ld_word(maskW, erodW, phase, m, gw + 3) : 0u;
                uint32_t carry = (aprev & bp) >> 31;
                uint32_t st = ov & ~((ov << 1) | carry);
                while (st) {
                    int p = __ffs(st) - 1; st &= st - 1;
                    lunion(lp, lbase + p, lbase + p + 128);
                }
            }
        }
        if (zl < 7) {
            uint32_t bz = ld_word(maskW, erodW, phase, m, gw + 512);
            uint32_t ov = a & bz;
            if (ov) {
                uint32_t bp = q ? ld_word(maskW, erodW, phase, m, gw + 511) : 0u;
                uint32_t carry = (aprev & bp) >> 31;
                uint32_t st = ov & ~((ov << 1) | carry);
                while (st) {
                    int p = __ffs(st) - 1; st &= st - 1;
                    lunion(lp, lbase + p, lbase + p + 1024);
                }
            }
        }
    }
    __syncthreads();

    // s3: roots allocate compact ids; mark root entries with -(node)-1
    int tileBase = tile * MAXC;
    {
        uint32_t st = a & ~(a << 1);
        while (st) {
            int p = __ffs(st) - 1; st &= st - 1;
            int h = lbase + p;
            if (lp[SW(h)] == h) {
                int k = atomicAdd(&lcount, 1);
                int node = tileBase + k;
                lp[SW(h)] = -node - 1;
                P[node] = node;                    // sparse parent init
            }
        }
    }
    __syncthreads();

    // s4: per run, walk to negative terminal (= -node-1), fill run, emit C
    {
        uint32_t wb = a;
        while (wb) {
            int p = __ffs(wb) - 1;
            uint32_t run = wb >> p;
            uint32_t inv = ~run;
            int len = inv ? (__ffs(inv) - 1) : (32 - p);
            int v = lp[SW(lbase + p)];
            while (v >= 0) v = lp[SW(v)];          // negatives are terminal
            for (int j = 0; j < len; ++j) lp[SW(lbase + p + j)] = v;
            if (p + len >= 32) break;
            wb &= ~(((1u << len) - 1u) << p);
        }
    }
    if (wl == 0) tcount[slot * NTILE + tile] = lcount;

    int gbase = gw << 5;
    int4* dst = (int4*)(C + gbase);
#pragma unroll
    for (int k = 0; k < 8; ++k) {
        int b0 = 4 * k;
        int4 v;
        v.x = ((a >> (b0 + 0)) & 1) ? (-lp[SW(lbase + b0 + 0)] - 1) : 0;
        v.y = ((a >> (b0 + 1)) & 1) ? (-lp[SW(lbase + b0 + 1)] - 1) : 0;
        v.z = ((a >> (b0 + 2)) & 1) ? (-lp[SW(lbase + b0 + 2)] - 1) : 0;
        v.w = ((a >> (b0 + 3)) & 1) ? (-lp[SW(lbase + b0 + 3)] - 1) : 0;
        dst[k] = v;
    }
}

// boundary merges on component ids: tile faces + phase-2 volume border.
__global__ void k_bmerge(const uint32_t* __restrict__ maskW, const uint32_t* __restrict__ erodW,
                         const int* __restrict__ Call, int* __restrict__ Pall, int m0) {
    int w = blockIdx.x * blockDim.x + threadIdx.x;     // 0 .. NWRD-1
    int slot = blockIdx.y;
    int pr = m0 + slot;
    int phase = pr / 12, m = pr % 12;
    int z = w >> 9, y = (w >> 2) & 127, q = w & 3;
    bool yface = ((y & 7) == 7) && y < 127;
    bool zface = ((z & 7) == 7) && z < 63;
    bool ph2 = (phase == 2);
    bool bord = ph2 && (z == 0 || z == 63 || y == 0 || y == 127);
    bool xbord = ph2 && (q == 0 || q == 3);
    if (!(yface || zface || bord || xbord)) return;

    const int* C = Call + (size_t)slot * NVOX;
    int* P = Pall + (size_t)slot * NODE_STRIDE;
    uint32_t a = ld_word(maskW, erodW, phase, m, w);
    if (!a) return;
    uint32_t aprev = q ? ld_word(maskW, erodW, phase, m, w - 1) : 0u;
    int i0 = w << 5;
    if (yface) {
        uint32_t by = ld_word(maskW, erodW, phase, m, w + 4);
        uint32_t ov = a & by;
        if (ov) {
            uint32_t bp = q ? ld_word(maskW, erodW, phase, m, w + 3) : 0u;
            uint32_t carry = (aprev & bp) >> 31;
            uint32_t st = ov & ~((ov << 1) | carry);
            int la = -1, lb = -1;
            while (st) {
                int p = __ffs(st) - 1; st &= st - 1;
                int ca = C[i0 + p], cb = C[i0 + p + WW];
                if (ca != la || cb != lb) { uf_union(P, ca, cb); la = ca; lb = cb; }
            }
        }
    }
    if (zface) {
        uint32_t bz = ld_word(maskW, erodW, phase, m, w + 512);
        uint32_t ov = a & bz;
        if (ov) {
            uint32_t bp = q ? ld_word(maskW, erodW, phase, m, w + 511) : 0u;
            uint32_t carry = (aprev & bp) >> 31;
            uint32_t st = ov & ~((ov << 1) | carry);
            int la = -1, lb = -1;
            while (st) {
                int p = __ffs(st) - 1; st &= st - 1;
                int ca = C[i0 + p], cb = C[i0 + p + HH * WW];
                if (ca != la || cb != lb) { uf_union(P, ca, cb); la = ca; lb = cb; }
            }
        }
    }
    if (bord) {
        uint32_t carry = aprev >> 31;
        uint32_t st = a & ~((a << 1) | carry);
        int la = -1;
        while (st) {
            int p = __ffs(st) - 1; st &= st - 1;
            int ca = C[i0 + p];
            if (ca != la) { uf_union(P, ca, VNODE); la = ca; }
        }
    } else if (xbord) {
        if (q == 0 && (a & 1u)) uf_union(P, C[i0], VNODE);
        if (q == 3 && (a >> 31)) uf_union(P, C[i0 + 31], VNODE);
    }
}

// phases 0/1: component count = roots among allocated ids.
__global__ void k_count01(const int* __restrict__ Pall, const int* __restrict__ tcount,
                          int* __restrict__ counts, int m0) {
    int slot = blockIdx.y;
    int pr = m0 + slot;
    int id = blockIdx.x * blockDim.x + threadIdx.x;    // 0 .. VNODE-1
    const int* P = Pall + (size_t)slot * NODE_STRIDE;
    int tile = id >> 12, k = id & (MAXC - 1);
    int tc = tcount[slot * NTILE + tile];
    int cnt = 0;
    if (k < tc && P[id] == id) cnt = 1;
    for (int off = 32; off; off >>= 1) cnt += __shfl_down(cnt, off);
    if ((threadIdx.x & 63) == 0 && cnt) atomicAdd(&counts[pr], cnt);
}

// phase 2: cavity volume = bg voxels whose component != border component.
__global__ void k_count2(const uint32_t* __restrict__ maskW,
                         const int* __restrict__ Call, int* __restrict__ Pall,
                         int* __restrict__ counts, int pr0, int slot0) {
    __shared__ int sRootV;
    int w = blockIdx.x * blockDim.x + threadIdx.x;
    int slot = slot0 + blockIdx.y;
    int pr = pr0 + blockIdx.y;
    int m = pr % 12;
    const int* C = Call + (size_t)slot * NVOX;
    int* P = Pall + (size_t)slot * NODE_STRIDE;
    if (threadIdx.x == 0) sRootV = uf_find_ro(P, VNODE);
    __syncthreads();
    uint32_t a = ~maskW[m * NWRD + w];
    int cnt = 0;
    if (a) {
        int i0 = w << 5;
        int rootV = sRootV;
        uint32_t st = a & ~(a << 1);
        while (st) {
            int p = __ffs(st) - 1; st &= st - 1;
            uint32_t run = a >> p;
            uint32_t inv = ~run;
            int len = inv ? (__ffs(inv) - 1) : (32 - p);
            if (uf_find_ro(P, C[i0 + p]) != rootV) cnt += len;
        }
    }
    for (int off = 32; off; off >>= 1) cnt += __shfl_down(cnt, off);
    if ((threadIdx.x & 63) == 0 && cnt) atomicAdd(&counts[pr], cnt);
}

__global__ void k_loss(const int* __restrict__ counts, float* __restrict__ out) {
    if (threadIdx.x != 0 || blockIdx.x != 0) return;
    float acc = 0.f;
    for (int m = 0; m < 6; ++m) {
        int pb0 = counts[m],      pbe = counts[12 + m],      pcv = counts[24 + m];
        int tb0 = counts[6 + m],  tbe = counts[12 + 6 + m],  tcv = counts[24 + 6 + m];
        int pb1 = max(0, pb0 - pbe), tb1 = max(0, tb0 - tbe);
        int pb2 = pcv / 100, tb2 = tcv / 100;
        acc += fabsf((float)(pb0 - tb0)) + fabsf((float)(pb1 - tb1)) + fabsf((float)(pb2 - tb2));
    }
    out[0] = 0.1f * acc / 6.0f;
}

// ---------------- launch ----------------
extern "C" void kernel_launch(void* const* d_in, const int* in_sizes, int n_in,
                              void* d_out, int out_size, void* d_ws, size_t ws_size,
                              hipStream_t stream) {
    const float* pred = (const float*)d_in[0];
    const int* tgt = (const int*)d_in[1];
    float* out = (float*)d_out;

    uint8_t* ws = (uint8_t*)d_ws;
    uint32_t* maskW = (uint32_t*)ws;
    size_t off = (size_t)NMASK * NWRD * 4;                 // 1.5 MB
    uint32_t* erodW = (uint32_t*)(ws + off);
    off += (size_t)NMASK * NWRD * 4;                       // +1.5 MB
    int* counts = (int*)(ws + off);
    off += 256;
    int* tcount = (int*)(ws + off);
    off += (size_t)NPROB * NTILE * 4;                      // 18 KB
    off = (off + 255) & ~(size_t)255;

    size_t avail = ws_size > off ? ws_size - off : 0;
    size_t slot_bytes = ((size_t)NVOX + NODE_STRIDE) * 4;  // 6.3 MB
    int PB = (int)(avail / slot_bytes);
    if (PB > NPROB) PB = NPROB;
    if (PB < 1) PB = 1;

    int* Call = (int*)(ws + off);
    int* Pall = Call + (size_t)PB * NVOX;

    k_masks2<<<dim3((BATCH * NVOX) / 256), 256, 0, stream>>>(pred, tgt, maskW, counts);
    k_erode<<<dim3((NMASK * NWRD) / 256), 256, 0, stream>>>(maskW, erodW);

    for (int m0 = 0; m0 < NPROB; m0 += PB) {
        int mb = PB < (NPROB - m0) ? PB : (NPROB - m0);
        k_local <<<dim3(NTILE, mb), 256, 0, stream>>>(maskW, erodW, Call, Pall, tcount, m0);
        k_bmerge<<<dim3(NWRD / 256, mb), 256, 0, stream>>>(maskW, erodW, Call, Pall, m0);
        int n01 = (m0 + mb < 24 ? m0 + mb : 24) - m0;
        if (n01 > 0)
            k_count01<<<dim3(VNODE / 256, n01), 256, 0, stream>>>(Pall, tcount, counts, m0);
        int lo2 = m0 > 24 ? m0 : 24;
        int n2 = (m0 + mb) - lo2;
        if (n2 > 0)
            k_count2<<<dim3(NWRD / 256, n2), 256, 0, stream>>>(maskW, Call, Pall, counts,
                                                               lo2, lo2 - m0);
    }

    k_loss<<<1, 64, 0, stream>>>(counts, out);
}

// Round 5
// 484.070 us; speedup vs baseline: 1.1487x; 1.1487x over previous
//
#include <hip/hip_runtime.h>
#include <stdint.h>

#define DD 64
#define HH 128
#define WW 128
#define NVOX (DD * HH * WW)      // 1<<20
#define NWRD (NVOX / 32)         // 32768 words per mask
#define BATCH 2
#define NCLS 4
#define NMASK 12                 // 6 pred then 6 target
#define NPROB 36                 // phase*12 + m ; phase: 0=mask 1=eroded 2=background
#define NTILE 128                // (HH/8)*(DD/8) tiles of 128x8x8 voxels
#define MAXC 4096                // max components per 8192-voxel tile (checkerboard bound)
#define VNODE (NTILE * MAXC)     // virtual border node id = 524288
#define NODE_STRIDE (VNODE + 64) // ints per component-parent slot

// ---------------- global lock-free union-find (on component ids) --------
__device__ __forceinline__ int uf_find(int* P, int x) {
    while (true) {
        int p = P[x];
        if (p == x) return x;
        int gp = P[p];
        if (gp != p) P[x] = gp;   // path halving (benign race; never demotes a root)
        x = gp;
    }
}
__device__ __forceinline__ int uf_find_ro(const int* P, int x) {
    int p;
    while ((p = P[x]) != x) x = p;
    return x;
}
// counting union: each successful CAS demotes exactly one root -> dec
__device__ __forceinline__ void uf_union(int* P, int a, int b, int* dec) {
    while (true) {
        a = uf_find(P, a);
        b = uf_find(P, b);
        if (a == b) return;
        int lo = a < b ? a : b;
        int hi = a < b ? b : a;
        int old = atomicCAS(&P[hi], hi, lo);
        if (old == hi) { if (dec) atomicSub(dec, 1); return; }
        a = lo; b = old;
    }
}

// ---------------- LDS union-find (swizzled: bank-conflict-free) ---------
#define SW(v) ((v) + ((v) >> 5))
__device__ __forceinline__ int lfind(int* lp, int x) {
    while (true) {
        int p = lp[SW(x)];
        if (p == x) return x;
        int gp = lp[SW(p)];
        if (gp != p) lp[SW(x)] = gp;
        x = gp;
    }
}
__device__ __forceinline__ void lunion(int* lp, int a, int b) {
    while (true) {
        a = lfind(lp, a);
        b = lfind(lp, b);
        if (a == b) return;
        int lo = a < b ? a : b;
        int hi = a < b ? b : a;
        int old = atomicCAS(&lp[SW(hi)], hi, lo);
        if (old == hi) return;
        a = lo; b = old;
    }
}

// word loader for problem (phase, m)
__device__ __forceinline__ uint32_t ld_word(const uint32_t* __restrict__ maskW,
                                            const uint32_t* __restrict__ erodW,
                                            int phase, int m, int w) {
    if (phase == 0) return maskW[m * NWRD + w];
    if (phase == 1) return erodW[m * NWRD + w];
    return ~maskW[m * NWRD + w];
}

// tile index of word w (tz*16 + ty)
__device__ __forceinline__ int tile_of_w(int w) {
    int z = w >> 9, y = (w >> 2) & 127;
    return (z >> 3) * 16 + (y >> 3);
}

// ---------------- kernels ----------------

// Build 12 bitpacked masks via ballot; zero counters.
__global__ void k_masks2(const float* __restrict__ pred, const int* __restrict__ tgt,
                         uint32_t* __restrict__ maskW, int* __restrict__ counts) {
    int tid = blockIdx.x * blockDim.x + threadIdx.x;   // 0 .. BATCH*NVOX-1
    if (tid < 64) counts[tid] = 0;
    int b = tid >> 20;
    int i = tid & (NVOX - 1);
    const float* p = pred + (size_t)b * NCLS * NVOX + i;
    float x0 = p[0], x1 = p[NVOX], x2 = p[2 * NVOX], x3 = p[3 * NVOX];
    float mx = fmaxf(fmaxf(x0, x1), fmaxf(x2, x3));
    float e0 = __expf(x0 - mx), e1 = __expf(x1 - mx), e2 = __expf(x2 - mx), e3 = __expf(x3 - mx);
    float S = e0 + e1 + e2 + e3;
    int t = tgt[(size_t)b * NVOX + i];
    int lane = threadIdx.x & 63;
    int wbase = i >> 5;
    float ev[3] = {e1, e2, e3};
    for (int c = 0; c < 3; ++c) {
        unsigned long long bal = __ballot(ev[c] / S > 0.5f);
        uint32_t* M = maskW + (size_t)(b * 3 + c) * NWRD;
        if (lane == 0)  M[wbase] = (uint32_t)bal;
        if (lane == 32) M[wbase] = (uint32_t)(bal >> 32);
        unsigned long long balT = __ballot(t == c + 1);
        uint32_t* MT = maskW + (size_t)(6 + b * 3 + c) * NWRD;
        if (lane == 0)  MT[wbase] = (uint32_t)balT;
        if (lane == 32) MT[wbase] = (uint32_t)(balT >> 32);
    }
}

// 6-conn binary erosion, border_value=0, bitwise.
__global__ void k_erode(const uint32_t* __restrict__ maskW, uint32_t* __restrict__ erodW) {
    int tid = blockIdx.x * blockDim.x + threadIdx.x;   // 0 .. 12*NWRD-1
    int m = tid / NWRD;
    int w = tid - m * NWRD;
    const uint32_t* M = maskW + (size_t)m * NWRD;
    int z = w >> 9, y = (w >> 2) & 127, q = w & 3;
    uint32_t a = M[w];
    uint32_t xl = (a << 1) | (q ? (M[w - 1] >> 31) : 0u);
    uint32_t xr = (a >> 1) | (q < 3 ? (M[w + 1] << 31) : 0u);
    uint32_t ym = (y > 0)   ? M[w - 4]   : 0u;
    uint32_t yp = (y < 127) ? M[w + 4]   : 0u;
    uint32_t zm = (z > 0)   ? M[w - 512] : 0u;
    uint32_t zp = (z < 63)  ? M[w + 512] : 0u;
    erodW[tid] = a & xl & xr & ym & yp & zm & zp;
}

// Tile-local CC (128x8x8 per block) in LDS; assigns per-tile local ids,
// writes uint16 voxel->local-id map, sparse parent init, and adds #components.
__global__ void k_local(const uint32_t* __restrict__ maskW, const uint32_t* __restrict__ erodW,
                        uint16_t* __restrict__ C16all, int* __restrict__ Pall,
                        int* __restrict__ counts, int m0) {
    __shared__ int lp[8448];         // swizzled 8192-entry local parent
    __shared__ int lcount;
    int slot = blockIdx.y;
    int pr = m0 + slot;
    int phase = pr / 12, m = pr % 12;
    uint16_t* C16 = C16all + (size_t)slot * NVOX;
    int* P = Pall + (size_t)slot * NODE_STRIDE;
    int tile = blockIdx.x;                         // 0..127
    int tz = tile >> 4, ty = tile & 15;
    int wl = threadIdx.x;                          // local word 0..255
    int zl = wl >> 5, yl = (wl >> 2) & 7, q = wl & 3;
    int gw = ((tz * 8 + zl) * 128 + (ty * 8 + yl)) * 4 + q;
    uint32_t a = ld_word(maskW, erodW, phase, m, gw);
    if (wl == 0) lcount = 0;
    if (blockIdx.x == 0 && wl == 0) P[VNODE] = VNODE;   // virtual border node

    // s1: x-run-head init within own word
    int lbase = wl << 5;
    {
        uint32_t wb = a;
        while (wb) {
            int p = __ffs(wb) - 1;
            uint32_t run = wb >> p;
            uint32_t inv = ~run;
            int len = inv ? (__ffs(inv) - 1) : (32 - p);
            for (int j = 0; j < len; ++j) lp[SW(lbase + p + j)] = lbase + p;
            if (p + len >= 32) break;
            wb &= ~(((1u << len) - 1u) << p);
        }
    }
    __syncthreads();

    // s2: intra-tile unions
    uint32_t aprev = q ? ld_word(maskW, erodW, phase, m, gw - 1) : 0u;
    if (a) {
        if (q && (a & 1u) && (aprev >> 31)) lunion(lp, lbase, lbase - 1);
        if (yl < 7) {
            uint32_t by = ld_word(maskW, erodW, phase, m, gw + 4);
            uint32_t ov = a & by;
            if (ov) {
                uint32_t bp = q ? ld_word(maskW, erodW, phase, m, gw + 3) : 0u;
                uint32_t carry = (aprev & bp) >> 31;
                uint32_t st = ov & ~((ov << 1) | carry);
                while (st) {
                    int p = __ffs(st) - 1; st &= st - 1;
                    lunion(lp, lbase + p, lbase + p + 128);
                }
            }
        }
        if (zl < 7) {
            uint32_t bz = ld_word(maskW, erodW, phase, m, gw + 512);
            uint32_t ov = a & bz;
            if (ov) {
                uint32_t bp = q ? ld_word(maskW, erodW, phase, m, gw + 511) : 0u;
                uint32_t carry = (aprev & bp) >> 31;
                uint32_t st = ov & ~((ov << 1) | carry);
                while (st) {
                    int p = __ffs(st) - 1; st &= st - 1;
                    lunion(lp, lbase + p, lbase + p + 1024);
                }
            }
        }
    }
    __syncthreads();

    // s3: roots allocate compact local ids; mark root entries with -(k)-1
    int tileBase = tile * MAXC;
    {
        uint32_t st = a & ~(a << 1);
        while (st) {
            int p = __ffs(st) - 1; st &= st - 1;
            int h = lbase + p;
            if (lp[SW(h)] == h) {
                int k = atomicAdd(&lcount, 1);
                lp[SW(h)] = -k - 1;
                P[tileBase + k] = tileBase + k;    // sparse parent init
            }
        }
    }
    __syncthreads();

    // s4: per run, walk to negative terminal (= -k-1), fill run
    {
        uint32_t wb = a;
        while (wb) {
            int p = __ffs(wb) - 1;
            uint32_t run = wb >> p;
            uint32_t inv = ~run;
            int len = inv ? (__ffs(inv) - 1) : (32 - p);
            int v = lp[SW(lbase + p)];
            while (v >= 0) v = lp[SW(v)];          // negatives are terminal
            for (int j = 0; j < len; ++j) lp[SW(lbase + p + j)] = v;
            if (p + len >= 32) break;
            wb &= ~(((1u << len) - 1u) << p);
        }
    }
    if (wl == 0 && phase < 2 && lcount) atomicAdd(&counts[pr], lcount);

    // emit uint16 local ids, vectorized (32 voxels -> 4x 16B stores)
    int gbase = gw << 5;
    uint32_t tmp[16];
#pragma unroll
    for (int k = 0; k < 16; ++k) {
        int b0 = 2 * k;
        uint32_t lo = ((a >> b0) & 1) ? (uint32_t)(-lp[SW(lbase + b0)] - 1) : 0u;
        uint32_t hi = ((a >> (b0 + 1)) & 1) ? (uint32_t)(-lp[SW(lbase + b0 + 1)] - 1) : 0u;
        tmp[k] = lo | (hi << 16);
    }
    uint4* dst = (uint4*)(C16 + gbase);
#pragma unroll
    for (int k = 0; k < 4; ++k)
        dst[k] = make_uint4(tmp[4 * k], tmp[4 * k + 1], tmp[4 * k + 2], tmp[4 * k + 3]);
}

// boundary merges on component ids: tile faces + phase-2 volume border.
__global__ void k_bmerge(const uint32_t* __restrict__ maskW, const uint32_t* __restrict__ erodW,
                         const uint16_t* __restrict__ C16all, int* __restrict__ Pall,
                         int* __restrict__ counts, int m0) {
    int w = blockIdx.x * blockDim.x + threadIdx.x;     // 0 .. NWRD-1
    int slot = blockIdx.y;
    int pr = m0 + slot;
    int phase = pr / 12, m = pr % 12;
    int z = w >> 9, y = (w >> 2) & 127, q = w & 3;
    bool yface = ((y & 7) == 7) && y < 127;
    bool zface = ((z & 7) == 7) && z < 63;
    bool ph2 = (phase == 2);
    bool bord = ph2 && (z == 0 || z == 63 || y == 0 || y == 127);
    bool xbord = ph2 && (q == 0 || q == 3);
    if (!(yface || zface || bord || xbord)) return;

    const uint16_t* C16 = C16all + (size_t)slot * NVOX;
    int* P = Pall + (size_t)slot * NODE_STRIDE;
    int* dec = (phase < 2) ? &counts[pr] : (int*)0;
    uint32_t a = ld_word(maskW, erodW, phase, m, w);
    if (!a) return;
    uint32_t aprev = q ? ld_word(maskW, erodW, phase, m, w - 1) : 0u;
    int i0 = w << 5;
    int tA = tile_of_w(w) * MAXC;
    if (yface) {
        uint32_t by = ld_word(maskW, erodW, phase, m, w + 4);
        uint32_t ov = a & by;
        if (ov) {
            int tB = tA + MAXC;                       // ty+1
            uint32_t bp = q ? ld_word(maskW, erodW, phase, m, w + 3) : 0u;
            uint32_t carry = (aprev & bp) >> 31;
            uint32_t st = ov & ~((ov << 1) | carry);
            int la = -1, lb = -1;
            while (st) {
                int p = __ffs(st) - 1; st &= st - 1;
                int ca = tA + C16[i0 + p], cb = tB + C16[i0 + p + WW];
                if (ca != la || cb != lb) { uf_union(P, ca, cb, dec); la = ca; lb = cb; }
            }
        }
    }
    if (zface) {
        uint32_t bz = ld_word(maskW, erodW, phase, m, w + 512);
        uint32_t ov = a & bz;
        if (ov) {
            int tB = tA + 16 * MAXC;                  // tz+1
            uint32_t bp = q ? ld_word(maskW, erodW, phase, m, w + 511) : 0u;
            uint32_t carry = (aprev & bp) >> 31;
            uint32_t st = ov & ~((ov << 1) | carry);
            int la = -1, lb = -1;
            while (st) {
                int p = __ffs(st) - 1; st &= st - 1;
                int ca = tA + C16[i0 + p], cb = tB + C16[i0 + p + HH * WW];
                if (ca != la || cb != lb) { uf_union(P, ca, cb, dec); la = ca; lb = cb; }
            }
        }
    }
    if (bord) {
        uint32_t carry = aprev >> 31;
        uint32_t st = a & ~((a << 1) | carry);
        int la = -1;
        while (st) {
            int p = __ffs(st) - 1; st &= st - 1;
            int ca = tA + C16[i0 + p];
            if (ca != la) { uf_union(P, ca, VNODE, (int*)0); la = ca; }
        }
    } else if (xbord) {
        if (q == 0 && (a & 1u)) uf_union(P, tA + C16[i0], VNODE, (int*)0);
        if (q == 3 && (a >> 31)) uf_union(P, tA + C16[i0 + 31], VNODE, (int*)0);
    }
}

// phase 2: cavity volume = bg voxels whose component != border component.
__global__ void k_count2(const uint32_t* __restrict__ maskW,
                         const uint16_t* __restrict__ C16all, int* __restrict__ Pall,
                         int* __restrict__ counts, int pr0, int slot0) {
    __shared__ int sRootV;
    int w = blockIdx.x * blockDim.x + threadIdx.x;
    int slot = slot0 + blockIdx.y;
    int pr = pr0 + blockIdx.y;
    int m = pr % 12;
    const uint16_t* C16 = C16all + (size_t)slot * NVOX;
    int* P = Pall + (size_t)slot * NODE_STRIDE;
    if (threadIdx.x == 0) sRootV = uf_find_ro(P, VNODE);
    __syncthreads();
    uint32_t a = ~maskW[m * NWRD + w];
    int cnt = 0;
    if (a) {
        int i0 = w << 5;
        int tA = tile_of_w(w) * MAXC;
        int rootV = sRootV;
        uint32_t st = a & ~(a << 1);
        while (st) {
            int p = __ffs(st) - 1; st &= st - 1;
            uint32_t run = a >> p;
            uint32_t inv = ~run;
            int len = inv ? (__ffs(inv) - 1) : (32 - p);
            if (uf_find_ro(P, tA + C16[i0 + p]) != rootV) cnt += len;
        }
    }
    for (int off = 32; off; off >>= 1) cnt += __shfl_down(cnt, off);
    if ((threadIdx.x & 63) == 0 && cnt) atomicAdd(&counts[pr], cnt);
}

__global__ void k_loss(const int* __restrict__ counts, float* __restrict__ out) {
    if (threadIdx.x != 0 || blockIdx.x != 0) return;
    float acc = 0.f;
    for (int m = 0; m < 6; ++m) {
        int pb0 = counts[m],      pbe = counts[12 + m],      pcv = counts[24 + m];
        int tb0 = counts[6 + m],  tbe = counts[12 + 6 + m],  tcv = counts[24 + 6 + m];
        int pb1 = max(0, pb0 - pbe), tb1 = max(0, tb0 - tbe);
        int pb2 = pcv / 100, tb2 = tcv / 100;
        acc += fabsf((float)(pb0 - tb0)) + fabsf((float)(pb1 - tb1)) + fabsf((float)(pb2 - tb2));
    }
    out[0] = 0.1f * acc / 6.0f;
}

// ---------------- launch ----------------
extern "C" void kernel_launch(void* const* d_in, const int* in_sizes, int n_in,
                              void* d_out, int out_size, void* d_ws, size_t ws_size,
                              hipStream_t stream) {
    const float* pred = (const float*)d_in[0];
    const int* tgt = (const int*)d_in[1];
    float* out = (float*)d_out;

    uint8_t* ws = (uint8_t*)d_ws;
    uint32_t* maskW = (uint32_t*)ws;
    size_t off = (size_t)NMASK * NWRD * 4;                 // 1.5 MB
    uint32_t* erodW = (uint32_t*)(ws + off);
    off += (size_t)NMASK * NWRD * 4;                       // +1.5 MB
    int* counts = (int*)(ws + off);
    off += 256;
    off = (off + 255) & ~(size_t)255;

    size_t avail = ws_size > off ? ws_size - off : 0;
    size_t slot_bytes = (size_t)NVOX * 2 + (size_t)NODE_STRIDE * 4;  // ~4.2 MB
    int PB = (int)(avail / slot_bytes);
    if (PB > NPROB) PB = NPROB;
    if (PB < 1) PB = 1;

    uint16_t* C16all = (uint16_t*)(ws + off);
    int* Pall = (int*)(ws + off + (size_t)PB * NVOX * 2);

    k_masks2<<<dim3((BATCH * NVOX) / 256), 256, 0, stream>>>(pred, tgt, maskW, counts);
    k_erode<<<dim3((NMASK * NWRD) / 256), 256, 0, stream>>>(maskW, erodW);

    for (int m0 = 0; m0 < NPROB; m0 += PB) {
        int mb = PB < (NPROB - m0) ? PB : (NPROB - m0);
        k_local <<<dim3(NTILE, mb), 256, 0, stream>>>(maskW, erodW, C16all, Pall, counts, m0);
        k_bmerge<<<dim3(NWRD / 256, mb), 256, 0, stream>>>(maskW, erodW, C16all, Pall, counts, m0);
        int lo2 = m0 > 24 ? m0 : 24;
        int n2 = (m0 + mb) - lo2;
        if (n2 > 0)
            k_count2<<<dim3(NWRD / 256, n2), 256, 0, stream>>>(maskW, C16all, Pall, counts,
                                                               lo2, lo2 - m0);
    }

    k_loss<<<1, 64, 0, stream>>>(counts, out);
}

// Round 6
// 328.540 us; speedup vs baseline: 1.6925x; 1.4734x over previous
//
#include <hip/hip_runtime.h>
#include <stdint.h>

#define DD 64
#define HH 128
#define WW 128
#define NVOX (DD * HH * WW)      // 1<<20
#define NWRD (NVOX / 32)         // 32768 words per mask
#define BATCH 2
#define NCLS 4
#define NMASK 12                 // 6 pred then 6 target
#define NPROB 36                 // phase*12 + m ; phase: 0=mask 1=eroded 2=background
#define NTILE 128                // (HH/8)*(DD/8) tiles of 128x8x8 voxels
#define MAXC 4096                // max components per 8192-voxel tile (checkerboard bound)
#define VNODE (NTILE * MAXC)     // virtual border node id = 524288
#define NODE_STRIDE (VNODE + 64) // ints per component-parent slot
#define NTASK 1856               // face row-crossings per problem: 15*64 y + 7*128 z

// ---------------- global lock-free union-find (on component ids) --------
__device__ __forceinline__ int uf_find(int* P, int x) {
    while (true) {
        int p = P[x];
        if (p == x) return x;
        int gp = P[p];
        if (gp != p) P[x] = gp;   // path halving (benign race; never demotes a root)
        x = gp;
    }
}
__device__ __forceinline__ int uf_find_ro(const int* P, int x) {
    int p;
    while ((p = P[x]) != x) x = p;
    return x;
}
// counting union: each successful CAS demotes exactly one root -> dec
__device__ __forceinline__ void uf_union(int* P, int a, int b, int* dec) {
    while (true) {
        a = uf_find(P, a);
        b = uf_find(P, b);
        if (a == b) return;
        int lo = a < b ? a : b;
        int hi = a < b ? b : a;
        int old = atomicCAS(&P[hi], hi, lo);
        if (old == hi) { if (dec) atomicSub(dec, 1); return; }
        a = lo; b = old;
    }
}

// ---------------- LDS union-find (swizzled: bank-conflict-free) ---------
#define SW(v) ((v) + ((v) >> 5))
__device__ __forceinline__ int lfind(int* lp, int x) {
    while (true) {
        int p = lp[SW(x)];
        if (p == x) return x;
        int gp = lp[SW(p)];
        if (gp != p) lp[SW(x)] = gp;
        x = gp;
    }
}
__device__ __forceinline__ void lunion(int* lp, int a, int b) {
    while (true) {
        a = lfind(lp, a);
        b = lfind(lp, b);
        if (a == b) return;
        int lo = a < b ? a : b;
        int hi = a < b ? b : a;
        int old = atomicCAS(&lp[SW(hi)], hi, lo);
        if (old == hi) return;
        a = lo; b = old;
    }
}

// word loader for problem (phase, m)
__device__ __forceinline__ uint32_t ld_word(const uint32_t* __restrict__ maskW,
                                            const uint32_t* __restrict__ erodW,
                                            int phase, int m, int w) {
    if (phase == 0) return maskW[m * NWRD + w];
    if (phase == 1) return erodW[m * NWRD + w];
    return ~maskW[m * NWRD + w];
}

// tile index of word w (tz*16 + ty)
__device__ __forceinline__ int tile_of_w(int w) {
    int z = w >> 9, y = (w >> 2) & 127;
    return (z >> 3) * 16 + (y >> 3);
}

// ---------------- kernels ----------------

// Build 12 bitpacked masks via ballot; zero counters.
__global__ void k_masks2(const float* __restrict__ pred, const int* __restrict__ tgt,
                         uint32_t* __restrict__ maskW, int* __restrict__ counts) {
    int tid = blockIdx.x * blockDim.x + threadIdx.x;   // 0 .. BATCH*NVOX-1
    if (tid < 64) counts[tid] = 0;
    int b = tid >> 20;
    int i = tid & (NVOX - 1);
    const float* p = pred + (size_t)b * NCLS * NVOX + i;
    float x0 = p[0], x1 = p[NVOX], x2 = p[2 * NVOX], x3 = p[3 * NVOX];
    float mx = fmaxf(fmaxf(x0, x1), fmaxf(x2, x3));
    float e0 = __expf(x0 - mx), e1 = __expf(x1 - mx), e2 = __expf(x2 - mx), e3 = __expf(x3 - mx);
    float S = e0 + e1 + e2 + e3;
    int t = tgt[(size_t)b * NVOX + i];
    int lane = threadIdx.x & 63;
    int wbase = i >> 5;
    float ev[3] = {e1, e2, e3};
    for (int c = 0; c < 3; ++c) {
        unsigned long long bal = __ballot(ev[c] / S > 0.5f);
        uint32_t* M = maskW + (size_t)(b * 3 + c) * NWRD;
        if (lane == 0)  M[wbase] = (uint32_t)bal;
        if (lane == 32) M[wbase] = (uint32_t)(bal >> 32);
        unsigned long long balT = __ballot(t == c + 1);
        uint32_t* MT = maskW + (size_t)(6 + b * 3 + c) * NWRD;
        if (lane == 0)  MT[wbase] = (uint32_t)balT;
        if (lane == 32) MT[wbase] = (uint32_t)(balT >> 32);
    }
}

// 6-conn binary erosion, border_value=0, bitwise.
__global__ void k_erode(const uint32_t* __restrict__ maskW, uint32_t* __restrict__ erodW) {
    int tid = blockIdx.x * blockDim.x + threadIdx.x;   // 0 .. 12*NWRD-1
    int m = tid / NWRD;
    int w = tid - m * NWRD;
    const uint32_t* M = maskW + (size_t)m * NWRD;
    int z = w >> 9, y = (w >> 2) & 127, q = w & 3;
    uint32_t a = M[w];
    uint32_t xl = (a << 1) | (q ? (M[w - 1] >> 31) : 0u);
    uint32_t xr = (a >> 1) | (q < 3 ? (M[w + 1] << 31) : 0u);
    uint32_t ym = (y > 0)   ? M[w - 4]   : 0u;
    uint32_t yp = (y < 127) ? M[w + 4]   : 0u;
    uint32_t zm = (z > 0)   ? M[w - 512] : 0u;
    uint32_t zp = (z < 63)  ? M[w + 512] : 0u;
    erodW[tid] = a & xl & xr & ym & yp & zm & zp;
}

// Tile-local CC (128x8x8 per block) in LDS; assigns per-tile local ids,
// writes uint16 voxel->local-id map, sparse parent init (+VNODE pre-link of
// volume-border components for phase 2), and adds #components (phases 0/1).
__global__ void k_local(const uint32_t* __restrict__ maskW, const uint32_t* __restrict__ erodW,
                        uint16_t* __restrict__ C16all, int* __restrict__ Pall,
                        int* __restrict__ counts, int* __restrict__ tcount, int m0) {
    __shared__ int lp[8448];         // swizzled 8192-entry local parent
    __shared__ int lcount;
    int slot = blockIdx.y;
    int pr = m0 + slot;
    int phase = pr / 12, m = pr % 12;
    uint16_t* C16 = C16all + (size_t)slot * NVOX;
    int* P = Pall + (size_t)slot * NODE_STRIDE;
    int tile = blockIdx.x;                         // 0..127
    int tz = tile >> 4, ty = tile & 15;
    int wl = threadIdx.x;                          // local word 0..255
    int zl = wl >> 5, yl = (wl >> 2) & 7, q = wl & 3;
    int gw = ((tz * 8 + zl) * 128 + (ty * 8 + yl)) * 4 + q;
    uint32_t a = ld_word(maskW, erodW, phase, m, gw);
    if (wl == 0) lcount = 0;
    if (blockIdx.x == 0 && wl == 0) P[VNODE] = VNODE;   // virtual border node

    // s1: x-run-head init within own word
    int lbase = wl << 5;
    {
        uint32_t wb = a;
        while (wb) {
            int p = __ffs(wb) - 1;
            uint32_t run = wb >> p;
            uint32_t inv = ~run;
            int len = inv ? (__ffs(inv) - 1) : (32 - p);
            for (int j = 0; j < len; ++j) lp[SW(lbase + p + j)] = lbase + p;
            if (p + len >= 32) break;
            wb &= ~(((1u << len) - 1u) << p);
        }
    }
    __syncthreads();

    // s2: intra-tile unions
    uint32_t aprev = q ? ld_word(maskW, erodW, phase, m, gw - 1) : 0u;
    if (a) {
        if (q && (a & 1u) && (aprev >> 31)) lunion(lp, lbase, lbase - 1);
        if (yl < 7) {
            uint32_t by = ld_word(maskW, erodW, phase, m, gw + 4);
            uint32_t ov = a & by;
            if (ov) {
                uint32_t bp = q ? ld_word(maskW, erodW, phase, m, gw + 3) : 0u;
                uint32_t carry = (aprev & bp) >> 31;
                uint32_t st = ov & ~((ov << 1) | carry);
                while (st) {
                    int p = __ffs(st) - 1; st &= st - 1;
                    lunion(lp, lbase + p, lbase + p + 128);
                }
            }
        }
        if (zl < 7) {
            uint32_t bz = ld_word(maskW, erodW, phase, m, gw + 512);
            uint32_t ov = a & bz;
            if (ov) {
                uint32_t bp = q ? ld_word(maskW, erodW, phase, m, gw + 511) : 0u;
                uint32_t carry = (aprev & bp) >> 31;
                uint32_t st = ov & ~((ov << 1) | carry);
                while (st) {
                    int p = __ffs(st) - 1; st &= st - 1;
                    lunion(lp, lbase + p, lbase + p + 1024);
                }
            }
        }
    }
    __syncthreads();

    // s3: roots allocate compact local ids; mark root entries with -(k)-1
    int tileBase = tile * MAXC;
    {
        uint32_t st = a & ~(a << 1);
        while (st) {
            int p = __ffs(st) - 1; st &= st - 1;
            int h = lbase + p;
            if (lp[SW(h)] == h) {
                int k = atomicAdd(&lcount, 1);
                lp[SW(h)] = -k - 1;
                P[tileBase + k] = tileBase + k;    // sparse parent init
            }
        }
    }
    __syncthreads();

    // s4: per run, walk to negative terminal (= -k-1), fill run
    {
        uint32_t wb = a;
        while (wb) {
            int p = __ffs(wb) - 1;
            uint32_t run = wb >> p;
            uint32_t inv = ~run;
            int len = inv ? (__ffs(inv) - 1) : (32 - p);
            int v = lp[SW(lbase + p)];
            while (v >= 0) v = lp[SW(v)];          // negatives are terminal
            for (int j = 0; j < len; ++j) lp[SW(lbase + p + j)] = v;
            if (p + len >= 32) break;
            wb &= ~(((1u << len) - 1u) << p);
        }
    }
    if (wl == 0) {
        tcount[slot * NTILE + tile] = lcount;
        if (phase < 2 && lcount) atomicAdd(&counts[pr], lcount);
    }

    // s5 (phase 2 only): pre-link volume-border components to VNODE.
    // Plain stores: overwrite s3's init (ordered by the s3 barrier); these
    // entries are never roots afterwards, so CAS-linking never targets them.
    if (phase == 2 && a) {
        int gz = tz * 8 + zl, gy = ty * 8 + yl;
        if (gz == 0 || gz == 63 || gy == 0 || gy == 127) {
            uint32_t st = a & ~(a << 1);
            while (st) {
                int p = __ffs(st) - 1; st &= st - 1;
                P[tileBase + (-lp[SW(lbase + p)] - 1)] = VNODE;
            }
        } else {
            if (q == 0 && (a & 1u))  P[tileBase + (-lp[SW(lbase)] - 1)] = VNODE;
            if (q == 3 && (a >> 31)) P[tileBase + (-lp[SW(lbase + 31)] - 1)] = VNODE;
        }
    }

    // emit uint16 local ids, vectorized (32 voxels -> 4x 16B stores)
    int gbase = gw << 5;
    uint32_t tmp[16];
#pragma unroll
    for (int k = 0; k < 16; ++k) {
        int b0 = 2 * k;
        uint32_t lo = ((a >> b0) & 1) ? (uint32_t)(-lp[SW(lbase + b0)] - 1) : 0u;
        uint32_t hi = ((a >> (b0 + 1)) & 1) ? (uint32_t)(-lp[SW(lbase + b0 + 1)] - 1) : 0u;
        tmp[k] = lo | (hi << 16);
    }
    uint4* dst = (uint4*)(C16 + gbase);
#pragma unroll
    for (int k = 0; k < 4; ++k)
        dst[k] = make_uint4(tmp[4 * k], tmp[4 * k + 1], tmp[4 * k + 2], tmp[4 * k + 3]);
}

// face merges: one thread per face row-crossing (full 128-voxel row), so the
// (ca,cb) dedup cache persists across the row and carry flows without bp loads.
__global__ void k_bmerge(const uint32_t* __restrict__ maskW, const uint32_t* __restrict__ erodW,
                         const uint16_t* __restrict__ C16all, int* __restrict__ Pall,
                         int* __restrict__ counts, int m0) {
    int t = blockIdx.x * blockDim.x + threadIdx.x;     // 0 .. NTASK-1
    if (t >= NTASK) return;
    int slot = blockIdx.y;
    int pr = m0 + slot;
    int phase = pr / 12, m = pr % 12;
    const uint16_t* C16 = C16all + (size_t)slot * NVOX;
    int* P = Pall + (size_t)slot * NODE_STRIDE;
    int* dec = (phase < 2) ? &counts[pr] : (int*)0;

    int w0, dw, dv, tA, tB;
    if (t < 960) {                      // y-face: y in {7,15,..,119}, z in 0..63
        int yi = t >> 6, z = t & 63;
        int y = 8 * yi + 7;
        w0 = (z * 128 + y) * 4;
        dw = 4; dv = WW;
        tA = ((z >> 3) * 16 + (y >> 3)) * MAXC;
        tB = tA + MAXC;
    } else {                            // z-face: z in {7,15,..,55}, y in 0..127
        int tt = t - 960;
        int zi = tt >> 7, y = tt & 127;
        int z = 8 * zi + 7;
        w0 = (z * 128 + y) * 4;
        dw = 512; dv = HH * WW;
        tA = ((z >> 3) * 16 + (y >> 3)) * MAXC;
        tB = tA + 16 * MAXC;
    }

    uint32_t carry = 0;
    int la = -1, lb = -1;
    for (int q = 0; q < 4; ++q) {
        int w = w0 + q;
        uint32_t a = ld_word(maskW, erodW, phase, m, w);
        uint32_t b = ld_word(maskW, erodW, phase, m, w + dw);
        uint32_t ov = a & b;
        if (ov) {
            uint32_t st = ov & ~((ov << 1) | carry);
            int i0 = w << 5;
            while (st) {
                int p = __ffs(st) - 1; st &= st - 1;
                int ca = tA + C16[i0 + p], cb = tB + C16[i0 + p + dv];
                if (ca != la || cb != lb) { uf_union(P, ca, cb, dec); la = ca; lb = cb; }
            }
        }
        carry = ov >> 31;
    }
}

// flatten allocated component entries (phase-2 slots) so finds become 1 load.
__global__ void k_flat(int* __restrict__ Pall, const int* __restrict__ tcount, int slot0) {
    int slot = slot0 + blockIdx.y;
    int tile = blockIdx.x;
    int* P = Pall + (size_t)slot * NODE_STRIDE;
    int lc = tcount[slot * NTILE + tile];
    for (int k = threadIdx.x; k < lc; k += blockDim.x) {
        int id = tile * MAXC + k;
        P[id] = uf_find_ro(P, id);
    }
    if (tile == 0 && threadIdx.x == 0) P[VNODE] = uf_find_ro(P, VNODE);
}

// phase 2: cavity volume = bg voxels whose component != border component.
__global__ void k_count2(const uint32_t* __restrict__ maskW,
                         const uint16_t* __restrict__ C16all, const int* __restrict__ Pall,
                         int* __restrict__ counts, int pr0, int slot0) {
    __shared__ int sRootV;
    int w = blockIdx.x * blockDim.x + threadIdx.x;
    int slot = slot0 + blockIdx.y;
    int pr = pr0 + blockIdx.y;
    int m = pr % 12;
    const uint16_t* C16 = C16all + (size_t)slot * NVOX;
    const int* P = Pall + (size_t)slot * NODE_STRIDE;
    if (threadIdx.x == 0) sRootV = P[VNODE];           // flattened
    __syncthreads();
    uint32_t a = ~maskW[m * NWRD + w];
    int cnt = 0;
    if (a) {
        int i0 = w << 5;
        int tA = tile_of_w(w) * MAXC;
        int rootV = sRootV;
        uint32_t st = a & ~(a << 1);
        while (st) {
            int p = __ffs(st) - 1; st &= st - 1;
            uint32_t run = a >> p;
            uint32_t inv = ~run;
            int len = inv ? (__ffs(inv) - 1) : (32 - p);
            if (P[tA + C16[i0 + p]] != rootV) cnt += len;   // flattened: 1 load
        }
    }
    for (int off = 32; off; off >>= 1) cnt += __shfl_down(cnt, off);
    if ((threadIdx.x & 63) == 0 && cnt) atomicAdd(&counts[pr], cnt);
}

__global__ void k_loss(const int* __restrict__ counts, float* __restrict__ out) {
    if (threadIdx.x != 0 || blockIdx.x != 0) return;
    float acc = 0.f;
    for (int m = 0; m < 6; ++m) {
        int pb0 = counts[m],      pbe = counts[12 + m],      pcv = counts[24 + m];
        int tb0 = counts[6 + m],  tbe = counts[12 + 6 + m],  tcv = counts[24 + 6 + m];
        int pb1 = max(0, pb0 - pbe), tb1 = max(0, tb0 - tbe);
        int pb2 = pcv / 100, tb2 = tcv / 100;
        acc += fabsf((float)(pb0 - tb0)) + fabsf((float)(pb1 - tb1)) + fabsf((float)(pb2 - tb2));
    }
    out[0] = 0.1f * acc / 6.0f;
}

// ---------------- launch ----------------
extern "C" void kernel_launch(void* const* d_in, const int* in_sizes, int n_in,
                              void* d_out, int out_size, void* d_ws, size_t ws_size,
                              hipStream_t stream) {
    const float* pred = (const float*)d_in[0];
    const int* tgt = (const int*)d_in[1];
    float* out = (float*)d_out;

    uint8_t* ws = (uint8_t*)d_ws;
    uint32_t* maskW = (uint32_t*)ws;
    size_t off = (size_t)NMASK * NWRD * 4;                 // 1.5 MB
    uint32_t* erodW = (uint32_t*)(ws + off);
    off += (size_t)NMASK * NWRD * 4;                       // +1.5 MB
    int* counts = (int*)(ws + off);
    off += 256;
    int* tcount = (int*)(ws + off);
    off += (size_t)NPROB * NTILE * 4;                      // 18 KB
    off = (off + 255) & ~(size_t)255;

    size_t avail = ws_size > off ? ws_size - off : 0;
    size_t slot_bytes = (size_t)NVOX * 2 + (size_t)NODE_STRIDE * 4;  // ~4.2 MB
    int PB = (int)(avail / slot_bytes);
    if (PB > NPROB) PB = NPROB;
    if (PB < 1) PB = 1;

    uint16_t* C16all = (uint16_t*)(ws + off);
    int* Pall = (int*)(ws + off + (size_t)PB * NVOX * 2);

    k_masks2<<<dim3((BATCH * NVOX) / 256), 256, 0, stream>>>(pred, tgt, maskW, counts);
    k_erode<<<dim3((NMASK * NWRD) / 256), 256, 0, stream>>>(maskW, erodW);

    for (int m0 = 0; m0 < NPROB; m0 += PB) {
        int mb = PB < (NPROB - m0) ? PB : (NPROB - m0);
        k_local <<<dim3(NTILE, mb), 256, 0, stream>>>(maskW, erodW, C16all, Pall,
                                                      counts, tcount, m0);
        k_bmerge<<<dim3((NTASK + 255) / 256, mb), 256, 0, stream>>>(maskW, erodW, C16all,
                                                                    Pall, counts, m0);
        int lo2 = m0 > 24 ? m0 : 24;
        int n2 = (m0 + mb) - lo2;
        if (n2 > 0) {
            k_flat  <<<dim3(NTILE, n2), 256, 0, stream>>>(Pall, tcount, lo2 - m0);
            k_count2<<<dim3(NWRD / 256, n2), 256, 0, stream>>>(maskW, C16all, Pall, counts,
                                                               lo2, lo2 - m0);
        }
    }

    k_loss<<<1, 64, 0, stream>>>(counts, out);
}

// Round 7
// 295.584 us; speedup vs baseline: 1.8812x; 1.1115x over previous
//
#include <hip/hip_runtime.h>
#include <stdint.h>

#define DD 64
#define HH 128
#define WW 128
#define NVOX (DD * HH * WW)      // 1<<20
#define NWRD (NVOX / 32)         // 32768 words per mask
#define BATCH 2
#define NCLS 4
#define NMASK 12                 // 6 pred then 6 target
#define NPROB 36                 // phase*12 + m ; phase: 0=mask 1=eroded 2=background
#define NTILE 128                // (HH/8)*(DD/8) tiles of 128x8x8 voxels
#define MAXC 4096                // max components per 8192-voxel tile (checkerboard bound)
#define VNODE (NTILE * MAXC)     // virtual border node id = 524288
#define NODE_STRIDE (VNODE + 64) // ints per component-parent slot
#define NTASK 1856               // face row-crossings per problem: 15*64 y + 7*128 z

// ---------------- global lock-free union-find (on component ids) --------
__device__ __forceinline__ int uf_find(int* P, int x) {
    while (true) {
        int p = P[x];
        if (p == x) return x;
        int gp = P[p];
        if (gp != p) P[x] = gp;   // path halving (benign race; never demotes a root)
        x = gp;
    }
}
__device__ __forceinline__ int uf_find_ro(const int* P, int x) {
    int p;
    while ((p = P[x]) != x) x = p;
    return x;
}
// counting union: each successful CAS demotes exactly one root -> dec
__device__ __forceinline__ void uf_union(int* P, int a, int b, int* dec) {
    while (true) {
        a = uf_find(P, a);
        b = uf_find(P, b);
        if (a == b) return;
        int lo = a < b ? a : b;
        int hi = a < b ? b : a;
        int old = atomicCAS(&P[hi], hi, lo);
        if (old == hi) { if (dec) atomicSub(dec, 1); return; }
        a = lo; b = old;
    }
}

// ---------------- LDS union-find on run heads (swizzled) ----------------
#define SW(v) ((v) + ((v) >> 5))
__device__ __forceinline__ int lfind(int* lp, int x) {
    while (true) {
        int p = lp[SW(x)];
        if (p == x) return x;
        int gp = lp[SW(p)];
        if (gp != p) lp[SW(x)] = gp;
        x = gp;
    }
}
__device__ __forceinline__ void lunion(int* lp, int a, int b) {
    while (true) {
        a = lfind(lp, a);
        b = lfind(lp, b);
        if (a == b) return;
        int lo = a < b ? a : b;
        int hi = a < b ? b : a;
        int old = atomicCAS(&lp[SW(hi)], hi, lo);
        if (old == hi) return;
        a = lo; b = old;
    }
}
// resolve a head to its component's compact id (root entries hold -k-1).
// Read-only: safe concurrently after the allocation barrier.
__device__ __forceinline__ int lresolve(const int* lp, int h) {
    int v = lp[SW(h)];
    while (v >= 0) v = lp[SW(v)];
    return -v - 1;
}
// start bit of the 1-run of w containing set bit p
__device__ __forceinline__ int run_head(uint32_t w, int p) {
    uint32_t below = ~w & ((1u << p) - 1u);
    return below ? (32 - __clz((int)below)) : 0;
}

// word loader for problem (phase, m)
__device__ __forceinline__ uint32_t ld_word(const uint32_t* __restrict__ maskW,
                                            const uint32_t* __restrict__ erodW,
                                            int phase, int m, int w) {
    if (phase == 0) return maskW[m * NWRD + w];
    if (phase == 1) return erodW[m * NWRD + w];
    return ~maskW[m * NWRD + w];
}

// tile index of word w (tz*16 + ty)
__device__ __forceinline__ int tile_of_w(int w) {
    int z = w >> 9, y = (w >> 2) & 127;
    return (z >> 3) * 16 + (y >> 3);
}

// ---------------- kernels ----------------

// Build 12 bitpacked masks via ballot; zero counters.
__global__ void k_masks2(const float* __restrict__ pred, const int* __restrict__ tgt,
                         uint32_t* __restrict__ maskW, int* __restrict__ counts) {
    int tid = blockIdx.x * blockDim.x + threadIdx.x;   // 0 .. BATCH*NVOX-1
    if (tid < 64) counts[tid] = 0;
    int b = tid >> 20;
    int i = tid & (NVOX - 1);
    const float* p = pred + (size_t)b * NCLS * NVOX + i;
    float x0 = p[0], x1 = p[NVOX], x2 = p[2 * NVOX], x3 = p[3 * NVOX];
    float mx = fmaxf(fmaxf(x0, x1), fmaxf(x2, x3));
    float e0 = __expf(x0 - mx), e1 = __expf(x1 - mx), e2 = __expf(x2 - mx), e3 = __expf(x3 - mx);
    float S = e0 + e1 + e2 + e3;
    int t = tgt[(size_t)b * NVOX + i];
    int lane = threadIdx.x & 63;
    int wbase = i >> 5;
    float ev[3] = {e1, e2, e3};
    for (int c = 0; c < 3; ++c) {
        unsigned long long bal = __ballot(ev[c] / S > 0.5f);
        uint32_t* M = maskW + (size_t)(b * 3 + c) * NWRD;
        if (lane == 0)  M[wbase] = (uint32_t)bal;
        if (lane == 32) M[wbase] = (uint32_t)(bal >> 32);
        unsigned long long balT = __ballot(t == c + 1);
        uint32_t* MT = maskW + (size_t)(6 + b * 3 + c) * NWRD;
        if (lane == 0)  MT[wbase] = (uint32_t)balT;
        if (lane == 32) MT[wbase] = (uint32_t)(balT >> 32);
    }
}

// 6-conn binary erosion, border_value=0, bitwise.
__global__ void k_erode(const uint32_t* __restrict__ maskW, uint32_t* __restrict__ erodW) {
    int tid = blockIdx.x * blockDim.x + threadIdx.x;   // 0 .. 12*NWRD-1
    int m = tid / NWRD;
    int w = tid - m * NWRD;
    const uint32_t* M = maskW + (size_t)m * NWRD;
    int z = w >> 9, y = (w >> 2) & 127, q = w & 3;
    uint32_t a = M[w];
    uint32_t xl = (a << 1) | (q ? (M[w - 1] >> 31) : 0u);
    uint32_t xr = (a >> 1) | (q < 3 ? (M[w + 1] << 31) : 0u);
    uint32_t ym = (y > 0)   ? M[w - 4]   : 0u;
    uint32_t yp = (y < 127) ? M[w + 4]   : 0u;
    uint32_t zm = (z > 0)   ? M[w - 512] : 0u;
    uint32_t zp = (z < 63)  ? M[w + 512] : 0u;
    erodW[tid] = a & xl & xr & ym & yp & zm & zp;
}

// Tile-local CC (128x8x8 per block): head-only LDS union-find, compact id
// allocation, demand-driven C16 emit, phase-2 border pre-link to VNODE.
__global__ void k_local(const uint32_t* __restrict__ maskW, const uint32_t* __restrict__ erodW,
                        uint16_t* __restrict__ C16all, int* __restrict__ Pall,
                        int* __restrict__ counts, int* __restrict__ tcount, int m0) {
    __shared__ int lp[8448];         // swizzled; only head entries are live
    __shared__ int lcount;
    int slot = blockIdx.y;
    int pr = m0 + slot;
    int phase = pr / 12, m = pr % 12;
    uint16_t* C16 = C16all + (size_t)slot * NVOX;
    int* P = Pall + (size_t)slot * NODE_STRIDE;
    int tile = blockIdx.x;                         // 0..127
    int tz = tile >> 4, ty = tile & 15;
    int wl = threadIdx.x;                          // local word 0..255
    int zl = wl >> 5, yl = (wl >> 2) & 7, q = wl & 3;
    int gw = ((tz * 8 + zl) * 128 + (ty * 8 + yl)) * 4 + q;
    uint32_t a = ld_word(maskW, erodW, phase, m, gw);
    if (wl == 0) lcount = 0;
    if (blockIdx.x == 0 && wl == 0) P[VNODE] = VNODE;   // virtual border node

    // s1: init head entries only
    int lbase = wl << 5;
    uint32_t heads = a & ~(a << 1);
    {
        uint32_t st = heads;
        while (st) { int p = __ffs(st) - 1; st &= st - 1; lp[SW(lbase + p)] = lbase + p; }
    }
    __syncthreads();

    // s2: intra-tile unions (head nodes; neighbor heads computed arithmetically)
    if (a) {
        if (q) {   // x link across word boundary within row
            uint32_t aprev = ld_word(maskW, erodW, phase, m, gw - 1);
            if ((a & 1u) && (aprev >> 31))
                lunion(lp, lbase, lbase - 32 + run_head(aprev, 31));
        }
        if (yl < 7) {
            uint32_t by = ld_word(maskW, erodW, phase, m, gw + 4);
            uint32_t ov = a & by;
            uint32_t st = ov & ~(ov << 1);
            int la = -1, lb = -1;
            while (st) {
                int p = __ffs(st) - 1; st &= st - 1;
                int ha = lbase + run_head(a, p);
                int hb = lbase + 128 + run_head(by, p);
                if (ha != la || hb != lb) { lunion(lp, ha, hb); la = ha; lb = hb; }
            }
        }
        if (zl < 7) {
            uint32_t bz = ld_word(maskW, erodW, phase, m, gw + 512);
            uint32_t ov = a & bz;
            uint32_t st = ov & ~(ov << 1);
            int la = -1, lb = -1;
            while (st) {
                int p = __ffs(st) - 1; st &= st - 1;
                int ha = lbase + run_head(a, p);
                int hb = lbase + 1024 + run_head(bz, p);
                if (ha != la || hb != lb) { lunion(lp, ha, hb); la = ha; lb = hb; }
            }
        }
    }
    __syncthreads();

    // s3: root heads allocate compact ids (root entry := -k-1)
    int tileBase = tile * MAXC;
    {
        uint32_t st = heads;
        while (st) {
            int p = __ffs(st) - 1; st &= st - 1;
            int h = lbase + p;
            if (lp[SW(h)] == h) {
                int k = atomicAdd(&lcount, 1);
                lp[SW(h)] = -k - 1;
                P[tileBase + k] = tileBase + k;    // sparse parent init
            }
        }
    }
    __syncthreads();

    if (wl == 0) {
        tcount[slot * NTILE + tile] = lcount;
        if (phase < 2 && lcount) atomicAdd(&counts[pr], lcount);
    }

    // s4: demand-driven emit + phase-2 VNODE pre-link.
    //  - phases 0/1: C16 needed only on tile-face rows (k_bmerge), full set bits.
    //  - phase 2: run-head entries everywhere (k_count2) + full face rows.
    //  - phase-2 volume-border / x-border components: P[c] = VNODE (plain store;
    //    these entries are never CAS targets afterwards).
    bool faceRow = (yl == 0 || yl == 7 || zl == 0 || zl == 7);
    if (a && (phase == 2 || faceRow)) {
        int i0 = gw << 5;
        int gz = tz * 8 + zl, gy = ty * 8 + yl;
        bool bordRow = (phase == 2) && (gz == 0 || gz == 63 || gy == 0 || gy == 127);
        if (faceRow && a == 0xFFFFFFFFu) {
            int id = lresolve(lp, lbase);
            uint32_t pk = (uint32_t)id * 0x10001u;
            uint4 v = make_uint4(pk, pk, pk, pk);
            uint4* dst = (uint4*)(C16 + i0);
            dst[0] = v; dst[1] = v; dst[2] = v; dst[3] = v;
            if (phase == 2 && (bordRow || q == 0 || q == 3))
                P[tileBase + id] = VNODE;
        } else {
            int h31 = (a >> 31) ? run_head(a, 31) : -1;
            uint32_t st = heads;
            while (st) {
                int p = __ffs(st) - 1; st &= st - 1;
                int id = lresolve(lp, lbase + p);
                C16[i0 + p] = (uint16_t)id;
                if (faceRow) {
                    uint32_t run = a >> p;
                    uint32_t inv = ~run;
                    int len = inv ? (__ffs(inv) - 1) : (32 - p);
                    for (int j = 1; j < len; ++j) C16[i0 + p + j] = (uint16_t)id;
                }
                if (phase == 2 &&
                    (bordRow || (q == 0 && p == 0) || (q == 3 && p == h31)))
                    P[tileBase + id] = VNODE;
            }
        }
    }
}

// face merges: one thread per face row-crossing (full 128-voxel row).
__global__ void k_bmerge(const uint32_t* __restrict__ maskW, const uint32_t* __restrict__ erodW,
                         const uint16_t* __restrict__ C16all, int* __restrict__ Pall,
                         int* __restrict__ counts, int m0) {
    int t = blockIdx.x * blockDim.x + threadIdx.x;     // 0 .. NTASK-1
    if (t >= NTASK) return;
    int slot = blockIdx.y;
    int pr = m0 + slot;
    int phase = pr / 12, m = pr % 12;
    const uint16_t* C16 = C16all + (size_t)slot * NVOX;
    int* P = Pall + (size_t)slot * NODE_STRIDE;
    int* dec = (phase < 2) ? &counts[pr] : (int*)0;

    int w0, dw, dv, tA, tB;
    if (t < 960) {                      // y-face: y in {7,15,..,119}, z in 0..63
        int yi = t >> 6, z = t & 63;
        int y = 8 * yi + 7;
        w0 = (z * 128 + y) * 4;
        dw = 4; dv = WW;
        tA = ((z >> 3) * 16 + (y >> 3)) * MAXC;
        tB = tA + MAXC;
    } else {                            // z-face: z in {7,15,..,55}, y in 0..127
        int tt = t - 960;
        int zi = tt >> 7, y = tt & 127;
        int z = 8 * zi + 7;
        w0 = (z * 128 + y) * 4;
        dw = 512; dv = HH * WW;
        tA = ((z >> 3) * 16 + (y >> 3)) * MAXC;
        tB = tA + 16 * MAXC;
    }

    uint32_t carry = 0;
    int la = -1, lb = -1;
    for (int q = 0; q < 4; ++q) {
        int w = w0 + q;
        uint32_t a = ld_word(maskW, erodW, phase, m, w);
        uint32_t b = ld_word(maskW, erodW, phase, m, w + dw);
        uint32_t ov = a & b;
        if (ov) {
            uint32_t st = ov & ~((ov << 1) | carry);
            int i0 = w << 5;
            while (st) {
                int p = __ffs(st) - 1; st &= st - 1;
                int ca = tA + C16[i0 + p], cb = tB + C16[i0 + p + dv];
                if (ca != la || cb != lb) { uf_union(P, ca, cb, dec); la = ca; lb = cb; }
            }
        }
        carry = ov >> 31;
    }
}

// flatten allocated component entries (phase-2 slots) so finds become 1 load.
__global__ void k_flat(int* __restrict__ Pall, const int* __restrict__ tcount, int slot0) {
    int slot = slot0 + blockIdx.y;
    int tile = blockIdx.x;
    int* P = Pall + (size_t)slot * NODE_STRIDE;
    int lc = tcount[slot * NTILE + tile];
    for (int k = threadIdx.x; k < lc; k += blockDim.x) {
        int id = tile * MAXC + k;
        P[id] = uf_find_ro(P, id);
    }
    if (tile == 0 && threadIdx.x == 0) P[VNODE] = uf_find_ro(P, VNODE);
}

// phase 2: cavity volume = bg voxels whose component != border component.
__global__ void k_count2(const uint32_t* __restrict__ maskW,
                         const uint16_t* __restrict__ C16all, const int* __restrict__ Pall,
                         int* __restrict__ counts, int pr0, int slot0) {
    __shared__ int sRootV;
    int w = blockIdx.x * blockDim.x + threadIdx.x;
    int slot = slot0 + blockIdx.y;
    int pr = pr0 + blockIdx.y;
    int m = pr % 12;
    const uint16_t* C16 = C16all + (size_t)slot * NVOX;
    const int* P = Pall + (size_t)slot * NODE_STRIDE;
    if (threadIdx.x == 0) sRootV = P[VNODE];           // flattened
    __syncthreads();
    uint32_t a = ~maskW[m * NWRD + w];
    int cnt = 0;
    if (a) {
        int i0 = w << 5;
        int tA = tile_of_w(w) * MAXC;
        int rootV = sRootV;
        uint32_t st = a & ~(a << 1);
        while (st) {
            int p = __ffs(st) - 1; st &= st - 1;
            uint32_t run = a >> p;
            uint32_t inv = ~run;
            int len = inv ? (__ffs(inv) - 1) : (32 - p);
            if (P[tA + C16[i0 + p]] != rootV) cnt += len;   // flattened: 1 load
        }
    }
    for (int off = 32; off; off >>= 1) cnt += __shfl_down(cnt, off);
    if ((threadIdx.x & 63) == 0 && cnt) atomicAdd(&counts[pr], cnt);
}

__global__ void k_loss(const int* __restrict__ counts, float* __restrict__ out) {
    if (threadIdx.x != 0 || blockIdx.x != 0) return;
    float acc = 0.f;
    for (int m = 0; m < 6; ++m) {
        int pb0 = counts[m],      pbe = counts[12 + m],      pcv = counts[24 + m];
        int tb0 = counts[6 + m],  tbe = counts[12 + 6 + m],  tcv = counts[24 + 6 + m];
        int pb1 = max(0, pb0 - pbe), tb1 = max(0, tb0 - tbe);
        int pb2 = pcv / 100, tb2 = tcv / 100;
        acc += fabsf((float)(pb0 - tb0)) + fabsf((float)(pb1 - tb1)) + fabsf((float)(pb2 - tb2));
    }
    out[0] = 0.1f * acc / 6.0f;
}

// ---------------- launch ----------------
extern "C" void kernel_launch(void* const* d_in, const int* in_sizes, int n_in,
                              void* d_out, int out_size, void* d_ws, size_t ws_size,
                              hipStream_t stream) {
    const float* pred = (const float*)d_in[0];
    const int* tgt = (const int*)d_in[1];
    float* out = (float*)d_out;

    uint8_t* ws = (uint8_t*)d_ws;
    uint32_t* maskW = (uint32_t*)ws;
    size_t off = (size_t)NMASK * NWRD * 4;                 // 1.5 MB
    uint32_t* erodW = (uint32_t*)(ws + off);
    off += (size_t)NMASK * NWRD * 4;                       // +1.5 MB
    int* counts = (int*)(ws + off);
    off += 256;
    int* tcount = (int*)(ws + off);
    off += (size_t)NPROB * NTILE * 4;                      // 18 KB
    off = (off + 255) & ~(size_t)255;

    size_t avail = ws_size > off ? ws_size - off : 0;
    size_t slot_bytes = (size_t)NVOX * 2 + (size_t)NODE_STRIDE * 4;  // ~4.2 MB
    int PB = (int)(avail / slot_bytes);
    if (PB > NPROB) PB = NPROB;
    if (PB < 1) PB = 1;

    uint16_t* C16all = (uint16_t*)(ws + off);
    int* Pall = (int*)(ws + off + (size_t)PB * NVOX * 2);

    k_masks2<<<dim3((BATCH * NVOX) / 256), 256, 0, stream>>>(pred, tgt, maskW, counts);
    k_erode<<<dim3((NMASK * NWRD) / 256), 256, 0, stream>>>(maskW, erodW);

    for (int m0 = 0; m0 < NPROB; m0 += PB) {
        int mb = PB < (NPROB - m0) ? PB : (NPROB - m0);
        k_local <<<dim3(NTILE, mb), 256, 0, stream>>>(maskW, erodW, C16all, Pall,
                                                      counts, tcount, m0);
        k_bmerge<<<dim3((NTASK + 255) / 256, mb), 256, 0, stream>>>(maskW, erodW, C16all,
                                                                    Pall, counts, m0);
        int lo2 = m0 > 24 ? m0 : 24;
        int n2 = (m0 + mb) - lo2;
        if (n2 > 0) {
            k_flat  <<<dim3(NTILE, n2), 256, 0, stream>>>(Pall, tcount, lo2 - m0);
            k_count2<<<dim3(NWRD / 256, n2), 256, 0, stream>>>(maskW, C16all, Pall, counts,
                                                               lo2, lo2 - m0);
        }
    }

    k_loss<<<1, 64, 0, stream>>>(counts, out);
}

// Round 8
// 289.956 us; speedup vs baseline: 1.9177x; 1.0194x over previous
//
#include <hip/hip_runtime.h>
#include <stdint.h>

#define DD 64
#define HH 128
#define WW 128
#define NVOX (DD * HH * WW)      // 1<<20
#define NWRD (NVOX / 32)         // 32768 words per mask
#define BATCH 2
#define NCLS 4
#define NMASK 12                 // 6 pred then 6 target
#define NPROB 36                 // phase*12 + m ; phase: 0=mask 1=eroded 2=background
#define NTILE 128                // (HH/8)*(DD/8) tiles of 128x8x8 voxels
#define MAXC 4096                // max components per 8192-voxel tile (checkerboard bound)
#define VNODE (NTILE * MAXC)     // virtual border node id = 524288
#define NODE_STRIDE (VNODE + 64) // ints per component-parent slot
#define NTASKW 7424              // face word-crossings per problem: 3840 y + 3584 z

// ---------------- global lock-free union-find (on component ids) --------
__device__ __forceinline__ int uf_find(int* P, int x) {
    while (true) {
        int p = P[x];
        if (p == x) return x;
        int gp = P[p];
        if (gp != p) P[x] = gp;   // path halving (benign race; never demotes a root)
        x = gp;
    }
}
__device__ __forceinline__ int uf_find_ro(const int* P, int x) {
    int p;
    while ((p = P[x]) != x) x = p;
    return x;
}
// counting union: each successful CAS demotes exactly one root -> dec.
// Idempotent & exactly-counted even under concurrent duplicate unions.
__device__ __forceinline__ void uf_union(int* P, int a, int b, int* dec) {
    while (true) {
        a = uf_find(P, a);
        b = uf_find(P, b);
        if (a == b) return;
        int lo = a < b ? a : b;
        int hi = a < b ? b : a;
        int old = atomicCAS(&P[hi], hi, lo);
        if (old == hi) { if (dec) atomicSub(dec, 1); return; }
        a = lo; b = old;
    }
}

// ---------------- LDS union-find on run heads (swizzled) ----------------
#define SW(v) ((v) + ((v) >> 5))
__device__ __forceinline__ int lfind(int* lp, int x) {
    while (true) {
        int p = lp[SW(x)];
        if (p == x) return x;
        int gp = lp[SW(p)];
        if (gp != p) lp[SW(x)] = gp;
        x = gp;
    }
}
__device__ __forceinline__ void lunion(int* lp, int a, int b) {
    while (true) {
        a = lfind(lp, a);
        b = lfind(lp, b);
        if (a == b) return;
        int lo = a < b ? a : b;
        int hi = a < b ? b : a;
        int old = atomicCAS(&lp[SW(hi)], hi, lo);
        if (old == hi) return;
        a = lo; b = old;
    }
}
// resolve a head to its component's compact id (root entries hold -k-1).
__device__ __forceinline__ int lresolve(const int* lp, int h) {
    int v = lp[SW(h)];
    while (v >= 0) v = lp[SW(v)];
    return -v - 1;
}
// start bit of the 1-run of w containing set bit p
__device__ __forceinline__ int run_head(uint32_t w, int p) {
    uint32_t below = ~w & ((1u << p) - 1u);
    return below ? (32 - __clz((int)below)) : 0;
}

// word loader for problem (phase, m)
__device__ __forceinline__ uint32_t ld_word(const uint32_t* __restrict__ maskW,
                                            const uint32_t* __restrict__ erodW,
                                            int phase, int m, int w) {
    if (phase == 0) return maskW[m * NWRD + w];
    if (phase == 1) return erodW[m * NWRD + w];
    return ~maskW[m * NWRD + w];
}

// tile index of word w (tz*16 + ty)
__device__ __forceinline__ int tile_of_w(int w) {
    int z = w >> 9, y = (w >> 2) & 127;
    return (z >> 3) * 16 + (y >> 3);
}

// ---------------- kernels ----------------

// Build 12 bitpacked masks via ballot; zero counters.
__global__ void k_masks2(const float* __restrict__ pred, const int* __restrict__ tgt,
                         uint32_t* __restrict__ maskW, int* __restrict__ counts) {
    int tid = blockIdx.x * blockDim.x + threadIdx.x;   // 0 .. BATCH*NVOX-1
    if (tid < 64) counts[tid] = 0;
    int b = tid >> 20;
    int i = tid & (NVOX - 1);
    const float* p = pred + (size_t)b * NCLS * NVOX + i;
    float x0 = p[0], x1 = p[NVOX], x2 = p[2 * NVOX], x3 = p[3 * NVOX];
    float mx = fmaxf(fmaxf(x0, x1), fmaxf(x2, x3));
    float e0 = __expf(x0 - mx), e1 = __expf(x1 - mx), e2 = __expf(x2 - mx), e3 = __expf(x3 - mx);
    float S = e0 + e1 + e2 + e3;
    int t = tgt[(size_t)b * NVOX + i];
    int lane = threadIdx.x & 63;
    int wbase = i >> 5;
    float ev[3] = {e1, e2, e3};
    for (int c = 0; c < 3; ++c) {
        unsigned long long bal = __ballot(ev[c] / S > 0.5f);
        uint32_t* M = maskW + (size_t)(b * 3 + c) * NWRD;
        if (lane == 0)  M[wbase] = (uint32_t)bal;
        if (lane == 32) M[wbase] = (uint32_t)(bal >> 32);
        unsigned long long balT = __ballot(t == c + 1);
        uint32_t* MT = maskW + (size_t)(6 + b * 3 + c) * NWRD;
        if (lane == 0)  MT[wbase] = (uint32_t)balT;
        if (lane == 32) MT[wbase] = (uint32_t)(balT >> 32);
    }
}

// 6-conn binary erosion, border_value=0, bitwise.
__global__ void k_erode(const uint32_t* __restrict__ maskW, uint32_t* __restrict__ erodW) {
    int tid = blockIdx.x * blockDim.x + threadIdx.x;   // 0 .. 12*NWRD-1
    int m = tid / NWRD;
    int w = tid - m * NWRD;
    const uint32_t* M = maskW + (size_t)m * NWRD;
    int z = w >> 9, y = (w >> 2) & 127, q = w & 3;
    uint32_t a = M[w];
    uint32_t xl = (a << 1) | (q ? (M[w - 1] >> 31) : 0u);
    uint32_t xr = (a >> 1) | (q < 3 ? (M[w + 1] << 31) : 0u);
    uint32_t ym = (y > 0)   ? M[w - 4]   : 0u;
    uint32_t yp = (y < 127) ? M[w + 4]   : 0u;
    uint32_t zm = (z > 0)   ? M[w - 512] : 0u;
    uint32_t zp = (z < 63)  ? M[w + 512] : 0u;
    erodW[tid] = a & xl & xr & ym & yp & zm & zp;
}

// Tile-local CC (128x8x8 per block): head-only LDS union-find, compact id
// allocation, demand-driven C16 emit, phase-2 border pre-link to VNODE.
__global__ void k_local(const uint32_t* __restrict__ maskW, const uint32_t* __restrict__ erodW,
                        uint16_t* __restrict__ C16all, int* __restrict__ Pall,
                        int* __restrict__ counts, int* __restrict__ tcount, int m0) {
    __shared__ int lp[8448];         // swizzled; only head entries are live
    __shared__ int lcount;
    int slot = blockIdx.y;
    int pr = m0 + slot;
    int phase = pr / 12, m = pr % 12;
    uint16_t* C16 = C16all + (size_t)slot * NVOX;
    int* P = Pall + (size_t)slot * NODE_STRIDE;
    int tile = blockIdx.x;                         // 0..127
    int tz = tile >> 4, ty = tile & 15;
    int wl = threadIdx.x;                          // local word 0..255
    int zl = wl >> 5, yl = (wl >> 2) & 7, q = wl & 3;
    int gw = ((tz * 8 + zl) * 128 + (ty * 8 + yl)) * 4 + q;
    uint32_t a = ld_word(maskW, erodW, phase, m, gw);
    if (wl == 0) lcount = 0;
    if (blockIdx.x == 0 && wl == 0) P[VNODE] = VNODE;   // virtual border node

    // s1: init head entries only
    int lbase = wl << 5;
    uint32_t heads = a & ~(a << 1);
    {
        uint32_t st = heads;
        while (st) { int p = __ffs(st) - 1; st &= st - 1; lp[SW(lbase + p)] = lbase + p; }
    }
    __syncthreads();

    // s2: intra-tile unions (head nodes; neighbor heads computed arithmetically)
    if (a) {
        if (q) {   // x link across word boundary within row
            uint32_t aprev = ld_word(maskW, erodW, phase, m, gw - 1);
            if ((a & 1u) && (aprev >> 31))
                lunion(lp, lbase, lbase - 32 + run_head(aprev, 31));
        }
        if (yl < 7) {
            uint32_t by = ld_word(maskW, erodW, phase, m, gw + 4);
            uint32_t ov = a & by;
            uint32_t st = ov & ~(ov << 1);
            int la = -1, lb = -1;
            while (st) {
                int p = __ffs(st) - 1; st &= st - 1;
                int ha = lbase + run_head(a, p);
                int hb = lbase + 128 + run_head(by, p);
                if (ha != la || hb != lb) { lunion(lp, ha, hb); la = ha; lb = hb; }
            }
        }
        if (zl < 7) {
            uint32_t bz = ld_word(maskW, erodW, phase, m, gw + 512);
            uint32_t ov = a & bz;
            uint32_t st = ov & ~(ov << 1);
            int la = -1, lb = -1;
            while (st) {
                int p = __ffs(st) - 1; st &= st - 1;
                int ha = lbase + run_head(a, p);
                int hb = lbase + 1024 + run_head(bz, p);
                if (ha != la || hb != lb) { lunion(lp, ha, hb); la = ha; lb = hb; }
            }
        }
    }
    __syncthreads();

    // s3: root heads allocate compact ids (root entry := -k-1)
    int tileBase = tile * MAXC;
    {
        uint32_t st = heads;
        while (st) {
            int p = __ffs(st) - 1; st &= st - 1;
            int h = lbase + p;
            if (lp[SW(h)] == h) {
                int k = atomicAdd(&lcount, 1);
                lp[SW(h)] = -k - 1;
                P[tileBase + k] = tileBase + k;    // sparse parent init
            }
        }
    }
    __syncthreads();

    if (wl == 0) {
        tcount[slot * NTILE + tile] = lcount;
        if (phase < 2 && lcount) atomicAdd(&counts[pr], lcount);
    }

    // s4: demand-driven emit + phase-2 VNODE pre-link.
    bool faceRow = (yl == 0 || yl == 7 || zl == 0 || zl == 7);
    if (a && (phase == 2 || faceRow)) {
        int i0 = gw << 5;
        int gz = tz * 8 + zl, gy = ty * 8 + yl;
        bool bordRow = (phase == 2) && (gz == 0 || gz == 63 || gy == 0 || gy == 127);
        if (faceRow && a == 0xFFFFFFFFu) {
            int id = lresolve(lp, lbase);
            uint32_t pk = (uint32_t)id * 0x10001u;
            uint4 v = make_uint4(pk, pk, pk, pk);
            uint4* dst = (uint4*)(C16 + i0);
            dst[0] = v; dst[1] = v; dst[2] = v; dst[3] = v;
            if (phase == 2 && (bordRow || q == 0 || q == 3))
                P[tileBase + id] = VNODE;
        } else {
            int h31 = (a >> 31) ? run_head(a, 31) : -1;
            uint32_t st = heads;
            while (st) {
                int p = __ffs(st) - 1; st &= st - 1;
                int id = lresolve(lp, lbase + p);
                C16[i0 + p] = (uint16_t)id;
                if (faceRow) {
                    uint32_t run = a >> p;
                    uint32_t inv = ~run;
                    int len = inv ? (__ffs(inv) - 1) : (32 - p);
                    for (int j = 1; j < len; ++j) C16[i0 + p + j] = (uint16_t)id;
                }
                if (phase == 2 &&
                    (bordRow || (q == 0 && p == 0) || (q == 3 && p == h31)))
                    P[tileBase + id] = VNODE;
            }
        }
    }
}

// face merges: one thread per face WORD-crossing (no cross-word carry:
// duplicate unions across word boundaries are idempotent and exactly counted).
__global__ void k_bmerge(const uint32_t* __restrict__ maskW, const uint32_t* __restrict__ erodW,
                         const uint16_t* __restrict__ C16all, int* __restrict__ Pall,
                         int* __restrict__ counts, int m0) {
    int t = blockIdx.x * blockDim.x + threadIdx.x;     // 0 .. NTASKW-1
    if (t >= NTASKW) return;
    int slot = blockIdx.y;
    int pr = m0 + slot;
    int phase = pr / 12, m = pr % 12;

    int w, dw, dv, tA, tB;
    if (t < 3840) {                     // y-face: yi in 0..14, z in 0..63, q in 0..3
        int q = t & 3, r = t >> 2;
        int yi = r >> 6, z = r & 63;
        int y = 8 * yi + 7;
        w = (z * 128 + y) * 4 + q;
        dw = 4; dv = WW;
        tA = ((z >> 3) * 16 + yi) * MAXC;
        tB = tA + MAXC;
    } else {                            // z-face: zi in 0..6, y in 0..127, q in 0..3
        int tt = t - 3840;
        int q = tt & 3, r = tt >> 2;
        int zi = r >> 7, y = r & 127;
        int z = 8 * zi + 7;
        w = (z * 128 + y) * 4 + q;
        dw = 512; dv = HH * WW;
        tA = (zi * 16 + (y >> 3)) * MAXC;
        tB = tA + 16 * MAXC;
    }

    uint32_t a = ld_word(maskW, erodW, phase, m, w);
    if (!a) return;
    uint32_t b = ld_word(maskW, erodW, phase, m, w + dw);
    uint32_t ov = a & b;
    if (!ov) return;

    const uint16_t* C16 = C16all + (size_t)slot * NVOX;
    int* P = Pall + (size_t)slot * NODE_STRIDE;
    int* dec = (phase < 2) ? &counts[pr] : (int*)0;
    uint32_t st = ov & ~(ov << 1);
    int i0 = w << 5;
    int la = -1, lb = -1;
    while (st) {
        int p = __ffs(st) - 1; st &= st - 1;
        int ca = tA + C16[i0 + p], cb = tB + C16[i0 + p + dv];
        if (ca != la || cb != lb) { uf_union(P, ca, cb, dec); la = ca; lb = cb; }
    }
}

// flatten allocated component entries (phase-2 slots) so finds become 1 load.
__global__ void k_flat(int* __restrict__ Pall, const int* __restrict__ tcount, int slot0) {
    int slot = slot0 + blockIdx.y;
    int tile = blockIdx.x;
    int* P = Pall + (size_t)slot * NODE_STRIDE;
    int lc = tcount[slot * NTILE + tile];
    for (int k = threadIdx.x; k < lc; k += blockDim.x) {
        int id = tile * MAXC + k;
        P[id] = uf_find_ro(P, id);
    }
    if (tile == 0 && threadIdx.x == 0) P[VNODE] = uf_find_ro(P, VNODE);
}

// phase 2: cavity volume = bg voxels whose component != border component.
__global__ void k_count2(const uint32_t* __restrict__ maskW,
                         const uint16_t* __restrict__ C16all, const int* __restrict__ Pall,
                         int* __restrict__ counts, int pr0, int slot0) {
    __shared__ int sRootV;
    int w = blockIdx.x * blockDim.x + threadIdx.x;
    int slot = slot0 + blockIdx.y;
    int pr = pr0 + blockIdx.y;
    int m = pr % 12;
    const uint16_t* C16 = C16all + (size_t)slot * NVOX;
    const int* P = Pall + (size_t)slot * NODE_STRIDE;
    if (threadIdx.x == 0) sRootV = P[VNODE];           // flattened
    __syncthreads();
    uint32_t a = ~maskW[m * NWRD + w];
    int cnt = 0;
    if (a) {
        int i0 = w << 5;
        int tA = tile_of_w(w) * MAXC;
        int rootV = sRootV;
        uint32_t st = a & ~(a << 1);
        while (st) {
            int p = __ffs(st) - 1; st &= st - 1;
            uint32_t run = a >> p;
            uint32_t inv = ~run;
            int len = inv ? (__ffs(inv) - 1) : (32 - p);
            if (P[tA + C16[i0 + p]] != rootV) cnt += len;   // flattened: 1 load
        }
    }
    for (int off = 32; off; off >>= 1) cnt += __shfl_down(cnt, off);
    if ((threadIdx.x & 63) == 0 && cnt) atomicAdd(&counts[pr], cnt);
}

__global__ void k_loss(const int* __restrict__ counts, float* __restrict__ out) {
    if (threadIdx.x != 0 || blockIdx.x != 0) return;
    float acc = 0.f;
    for (int m = 0; m < 6; ++m) {
        int pb0 = counts[m],      pbe = counts[12 + m],      pcv = counts[24 + m];
        int tb0 = counts[6 + m],  tbe = counts[12 + 6 + m],  tcv = counts[24 + 6 + m];
        int pb1 = max(0, pb0 - pbe), tb1 = max(0, tb0 - tbe);
        int pb2 = pcv / 100, tb2 = tcv / 100;
        acc += fabsf((float)(pb0 - tb0)) + fabsf((float)(pb1 - tb1)) + fabsf((float)(pb2 - tb2));
    }
    out[0] = 0.1f * acc / 6.0f;
}

// ---------------- launch ----------------
extern "C" void kernel_launch(void* const* d_in, const int* in_sizes, int n_in,
                              void* d_out, int out_size, void* d_ws, size_t ws_size,
                              hipStream_t stream) {
    const float* pred = (const float*)d_in[0];
    const int* tgt = (const int*)d_in[1];
    float* out = (float*)d_out;

    uint8_t* ws = (uint8_t*)d_ws;
    uint32_t* maskW = (uint32_t*)ws;
    size_t off = (size_t)NMASK * NWRD * 4;                 // 1.5 MB
    uint32_t* erodW = (uint32_t*)(ws + off);
    off += (size_t)NMASK * NWRD * 4;                       // +1.5 MB
    int* counts = (int*)(ws + off);
    off += 256;
    int* tcount = (int*)(ws + off);
    off += (size_t)NPROB * NTILE * 4;                      // 18 KB
    off = (off + 255) & ~(size_t)255;

    size_t avail = ws_size > off ? ws_size - off : 0;
    size_t slot_bytes = (size_t)NVOX * 2 + (size_t)NODE_STRIDE * 4;  // ~4.2 MB
    int PB = (int)(avail / slot_bytes);
    if (PB > NPROB) PB = NPROB;
    if (PB < 1) PB = 1;

    uint16_t* C16all = (uint16_t*)(ws + off);
    int* Pall = (int*)(ws + off + (size_t)PB * NVOX * 2);

    k_masks2<<<dim3((BATCH * NVOX) / 256), 256, 0, stream>>>(pred, tgt, maskW, counts);
    k_erode<<<dim3((NMASK * NWRD) / 256), 256, 0, stream>>>(maskW, erodW);

    for (int m0 = 0; m0 < NPROB; m0 += PB) {
        int mb = PB < (NPROB - m0) ? PB : (NPROB - m0);
        k_local <<<dim3(NTILE, mb), 256, 0, stream>>>(maskW, erodW, C16all, Pall,
                                                      counts, tcount, m0);
        k_bmerge<<<dim3((NTASKW + 255) / 256, mb), 256, 0, stream>>>(maskW, erodW, C16all,
                                                                     Pall, counts, m0);
        int lo2 = m0 > 24 ? m0 : 24;
        int n2 = (m0 + mb) - lo2;
        if (n2 > 0) {
            k_flat  <<<dim3(NTILE, n2), 256, 0, stream>>>(Pall, tcount, lo2 - m0);
            k_count2<<<dim3(NWRD / 256, n2), 256, 0, stream>>>(maskW, C16all, Pall, counts,
                                                               lo2, lo2 - m0);
        }
    }

    k_loss<<<1, 64, 0, stream>>>(counts, out);
}

// Round 9
// 274.305 us; speedup vs baseline: 2.0271x; 1.0571x over previous
//
#include <hip/hip_runtime.h>
#include <stdint.h>

#define DD 64
#define HH 128
#define WW 128
#define NVOX (DD * HH * WW)      // 1<<20
#define NWRD (NVOX / 32)         // 32768 words per mask
#define BATCH 2
#define NCLS 4
#define NMASK 12                 // 6 pred then 6 target
#define NPROB 36                 // phase*12 + m ; phase: 0=mask 1=eroded 2=background
#define NTILE 128                // (HH/8)*(DD/8) tiles of 128x8x8 voxels
#define MAXC 4096                // max components per 8192-voxel tile (checkerboard bound)
#define VNODE (NTILE * MAXC)     // virtual border node id = 524288
#define NODE_STRIDE (VNODE + 64) // ints per component-parent slot
#define NTASKW 7424              // face word-crossings per problem: 3840 y + 3584 z

// ---------------- global lock-free union-find (on component ids) --------
__device__ __forceinline__ int uf_find(int* P, int x) {
    while (true) {
        int p = P[x];
        if (p == x) return x;
        int gp = P[p];
        if (gp != p) P[x] = gp;   // path halving (benign race; never demotes a root)
        x = gp;
    }
}
__device__ __forceinline__ int uf_find_ro(const int* P, int x) {
    int p;
    while ((p = P[x]) != x) x = p;
    return x;
}
// counting union: each successful CAS demotes exactly one root -> dec.
__device__ __forceinline__ void uf_union(int* P, int a, int b, int* dec) {
    while (true) {
        a = uf_find(P, a);
        b = uf_find(P, b);
        if (a == b) return;
        int lo = a < b ? a : b;
        int hi = a < b ? b : a;
        int old = atomicCAS(&P[hi], hi, lo);
        if (old == hi) { if (dec) atomicSub(dec, 1); return; }
        a = lo; b = old;
    }
}

// ---------------- LDS union-find on half-word run heads (swizzled) ------
#define SW(v) ((v) + ((v) >> 5))
__device__ __forceinline__ int lfind(int* lp, int x) {
    while (true) {
        int p = lp[SW(x)];
        if (p == x) return x;
        int gp = lp[SW(p)];
        if (gp != p) lp[SW(x)] = gp;
        x = gp;
    }
}
__device__ __forceinline__ void lunion(int* lp, int a, int b) {
    while (true) {
        a = lfind(lp, a);
        b = lfind(lp, b);
        if (a == b) return;
        int lo = a < b ? a : b;
        int hi = a < b ? b : a;
        int old = atomicCAS(&lp[SW(hi)], hi, lo);
        if (old == hi) return;
        a = lo; b = old;
    }
}
// resolve a head to its component's compact id (root entries hold -k-1).
__device__ __forceinline__ int lresolve(const int* lp, int h) {
    int v = lp[SW(h)];
    while (v >= 0) v = lp[SW(v)];
    return -v - 1;
}
// start bit of the 1-run of w containing set bit p (works for 16/32-bit w)
__device__ __forceinline__ int run_head(uint32_t w, int p) {
    uint32_t below = ~w & ((1u << p) - 1u);
    return below ? (32 - __clz((int)below)) : 0;
}

// word loader for problem (phase, m)
__device__ __forceinline__ uint32_t ld_word(const uint32_t* __restrict__ maskW,
                                            const uint32_t* __restrict__ erodW,
                                            int phase, int m, int w) {
    if (phase == 0) return maskW[m * NWRD + w];
    if (phase == 1) return erodW[m * NWRD + w];
    return ~maskW[m * NWRD + w];
}

// tile index of word w (tz*16 + ty)
__device__ __forceinline__ int tile_of_w(int w) {
    int z = w >> 9, y = (w >> 2) & 127;
    return (z >> 3) * 16 + (y >> 3);
}

// ---------------- kernels ----------------

// Build 12 bitpacked masks via ballot; zero counters.
__global__ void k_masks2(const float* __restrict__ pred, const int* __restrict__ tgt,
                         uint32_t* __restrict__ maskW, int* __restrict__ counts) {
    int tid = blockIdx.x * blockDim.x + threadIdx.x;   // 0 .. BATCH*NVOX-1
    if (tid < 64) counts[tid] = 0;
    int b = tid >> 20;
    int i = tid & (NVOX - 1);
    const float* p = pred + (size_t)b * NCLS * NVOX + i;
    float x0 = p[0], x1 = p[NVOX], x2 = p[2 * NVOX], x3 = p[3 * NVOX];
    float mx = fmaxf(fmaxf(x0, x1), fmaxf(x2, x3));
    float e0 = __expf(x0 - mx), e1 = __expf(x1 - mx), e2 = __expf(x2 - mx), e3 = __expf(x3 - mx);
    float S = e0 + e1 + e2 + e3;
    int t = tgt[(size_t)b * NVOX + i];
    int lane = threadIdx.x & 63;
    int wbase = i >> 5;
    float ev[3] = {e1, e2, e3};
    for (int c = 0; c < 3; ++c) {
        unsigned long long bal = __ballot(ev[c] / S > 0.5f);
        uint32_t* M = maskW + (size_t)(b * 3 + c) * NWRD;
        if (lane == 0)  M[wbase] = (uint32_t)bal;
        if (lane == 32) M[wbase] = (uint32_t)(bal >> 32);
        unsigned long long balT = __ballot(t == c + 1);
        uint32_t* MT = maskW + (size_t)(6 + b * 3 + c) * NWRD;
        if (lane == 0)  MT[wbase] = (uint32_t)balT;
        if (lane == 32) MT[wbase] = (uint32_t)(balT >> 32);
    }
}

// 6-conn binary erosion, border_value=0, bitwise.
__global__ void k_erode(const uint32_t* __restrict__ maskW, uint32_t* __restrict__ erodW) {
    int tid = blockIdx.x * blockDim.x + threadIdx.x;   // 0 .. 12*NWRD-1
    int m = tid / NWRD;
    int w = tid - m * NWRD;
    const uint32_t* M = maskW + (size_t)m * NWRD;
    int z = w >> 9, y = (w >> 2) & 127, q = w & 3;
    uint32_t a = M[w];
    uint32_t xl = (a << 1) | (q ? (M[w - 1] >> 31) : 0u);
    uint32_t xr = (a >> 1) | (q < 3 ? (M[w + 1] << 31) : 0u);
    uint32_t ym = (y > 0)   ? M[w - 4]   : 0u;
    uint32_t yp = (y < 127) ? M[w + 4]   : 0u;
    uint32_t zm = (z > 0)   ? M[w - 512] : 0u;
    uint32_t zp = (z < 63)  ? M[w + 512] : 0u;
    erodW[tid] = a & xl & xr & ym & yp & zm & zp;
}

// Tile-local CC (128x8x8 per block, 512 threads = one per 16-bit half-word):
// head-only LDS union-find, compact id allocation, demand-driven C16 emit,
// phase-2 border pre-link to VNODE.
__global__ void k_local(const uint32_t* __restrict__ maskW, const uint32_t* __restrict__ erodW,
                        uint16_t* __restrict__ C16all, int* __restrict__ Pall,
                        int* __restrict__ counts, int* __restrict__ tcount, int m0) {
    __shared__ int lp[8448];         // swizzled; only half-run-head entries live
    __shared__ int lcount;
    int slot = blockIdx.y;
    int pr = m0 + slot;
    int phase = pr / 12, m = pr % 12;
    uint16_t* C16 = C16all + (size_t)slot * NVOX;
    int* P = Pall + (size_t)slot * NODE_STRIDE;
    int tile = blockIdx.x;                         // 0..127
    int tz = tile >> 4, ty = tile & 15;
    int t2 = threadIdx.x;                          // 0..511 : half-word index
    int wl = t2 >> 1;                              // local word 0..255
    int h  = t2 & 1;                               // half within word
    int zl = wl >> 5, yl = (wl >> 2) & 7, q = wl & 3;
    int gw = ((tz * 8 + zl) * 128 + (ty * 8 + yl)) * 4 + q;
    uint32_t afull = ld_word(maskW, erodW, phase, m, gw);
    uint32_t a16 = (afull >> (16 * h)) & 0xFFFFu;
    if (t2 == 0) lcount = 0;
    if (blockIdx.x == 0 && t2 == 0) P[VNODE] = VNODE;   // virtual border node

    // s1: init half-run-head entries only
    int lbase = t2 << 4;
    uint32_t heads = a16 & ~(a16 << 1) & 0xFFFFu;
    {
        uint32_t st = heads;
        while (st) { int p = __ffs(st) - 1; st &= st - 1; lp[SW(lbase + p)] = lbase + p; }
    }
    __syncthreads();

    // s2: intra-tile unions (half-head nodes; neighbor heads arithmetic)
    if (a16) {
        if (a16 & 1u) {            // x link to previous half / previous word
            if (h == 1) {
                uint32_t lo16 = afull & 0xFFFFu;
                if (lo16 >> 15) lunion(lp, lbase, lbase - 16 + run_head(lo16, 15));
            } else if (q) {
                uint32_t hi16 = ld_word(maskW, erodW, phase, m, gw - 1) >> 16;
                if (hi16 >> 15) lunion(lp, lbase, lbase - 16 + run_head(hi16, 15));
            }
        }
        if (yl < 7) {
            uint32_t by = (ld_word(maskW, erodW, phase, m, gw + 4) >> (16 * h)) & 0xFFFFu;
            uint32_t ov = a16 & by;
            uint32_t st = ov & ~(ov << 1);
            int la = -1, lb = -1;
            while (st) {
                int p = __ffs(st) - 1; st &= st - 1;
                int ha = lbase + run_head(a16, p);
                int hb = lbase + 128 + run_head(by, p);     // word+4 -> +8 halves
                if (ha != la || hb != lb) { lunion(lp, ha, hb); la = ha; lb = hb; }
            }
        }
        if (zl < 7) {
            uint32_t bz = (ld_word(maskW, erodW, phase, m, gw + 512) >> (16 * h)) & 0xFFFFu;
            uint32_t ov = a16 & bz;
            uint32_t st = ov & ~(ov << 1);
            int la = -1, lb = -1;
            while (st) {
                int p = __ffs(st) - 1; st &= st - 1;
                int ha = lbase + run_head(a16, p);
                int hb = lbase + 1024 + run_head(bz, p);    // word+32 -> +64 halves
                if (ha != la || hb != lb) { lunion(lp, ha, hb); la = ha; lb = hb; }
            }
        }
    }
    __syncthreads();

    // s3: root heads allocate compact ids (root entry := -k-1)
    int tileBase = tile * MAXC;
    {
        uint32_t st = heads;
        while (st) {
            int p = __ffs(st) - 1; st &= st - 1;
            int hh = lbase + p;
            if (lp[SW(hh)] == hh) {
                int k = atomicAdd(&lcount, 1);
                lp[SW(hh)] = -k - 1;
                P[tileBase + k] = tileBase + k;    // sparse parent init
            }
        }
    }
    __syncthreads();

    if (t2 == 0) {
        tcount[slot * NTILE + tile] = lcount;
        if (phase < 2 && lcount) atomicAdd(&counts[pr], lcount);
    }

    // s4: demand-driven emit + phase-2 VNODE pre-link.
    //  - every word-level run head is also a half-level head, so consumers'
    //    read positions are always written.
    bool faceRow = (yl == 0 || yl == 7 || zl == 0 || zl == 7);
    if (a16 && (phase == 2 || faceRow)) {
        int i0 = (gw << 5) + 16 * h;
        int gz = tz * 8 + zl, gy = ty * 8 + yl;
        bool bordRow = (phase == 2) && (gz == 0 || gz == 63 || gy == 0 || gy == 127);
        if (faceRow && a16 == 0xFFFFu) {
            int id = lresolve(lp, lbase);
            uint32_t pk = (uint32_t)id * 0x10001u;
            uint4 v = make_uint4(pk, pk, pk, pk);
            uint4* dst = (uint4*)(C16 + i0);
            dst[0] = v; dst[1] = v;
            if (phase == 2 && (bordRow || (q == 0 && h == 0) || (q == 3 && h == 1)))
                P[tileBase + id] = VNODE;
        } else {
            int htop = (a16 >> 15) ? run_head(a16, 15) : -1;
            uint32_t st = heads;
            while (st) {
                int p = __ffs(st) - 1; st &= st - 1;
                int id = lresolve(lp, lbase + p);
                C16[i0 + p] = (uint16_t)id;
                if (faceRow) {
                    uint32_t run = a16 >> p;
                    int len = __ffs(~run) - 1;       // run < 2^16 so ~run != 0
                    for (int j = 1; j < len; ++j) C16[i0 + p + j] = (uint16_t)id;
                }
                if (phase == 2 &&
                    (bordRow || (q == 0 && h == 0 && p == 0) ||
                     (q == 3 && h == 1 && p == htop)))
                    P[tileBase + id] = VNODE;
            }
        }
    }
}

// face merges: one thread per face WORD-crossing (no cross-word carry:
// duplicate unions across word boundaries are idempotent and exactly counted).
__global__ void k_bmerge(const uint32_t* __restrict__ maskW, const uint32_t* __restrict__ erodW,
                         const uint16_t* __restrict__ C16all, int* __restrict__ Pall,
                         int* __restrict__ counts, int m0) {
    int t = blockIdx.x * blockDim.x + threadIdx.x;     // 0 .. NTASKW-1
    if (t >= NTASKW) return;
    int slot = blockIdx.y;
    int pr = m0 + slot;
    int phase = pr / 12, m = pr % 12;

    int w, dw, dv, tA, tB;
    if (t < 3840) {                     // y-face: yi in 0..14, z in 0..63, q in 0..3
        int q = t & 3, r = t >> 2;
        int yi = r >> 6, z = r & 63;
        int y = 8 * yi + 7;
        w = (z * 128 + y) * 4 + q;
        dw = 4; dv = WW;
        tA = ((z >> 3) * 16 + yi) * MAXC;
        tB = tA + MAXC;
    } else {                            // z-face: zi in 0..6, y in 0..127, q in 0..3
        int tt = t - 3840;
        int q = tt & 3, r = tt >> 2;
        int zi = r >> 7, y = r & 127;
        int z = 8 * zi + 7;
        w = (z * 128 + y) * 4 + q;
        dw = 512; dv = HH * WW;
        tA = (zi * 16 + (y >> 3)) * MAXC;
        tB = tA + 16 * MAXC;
    }

    uint32_t a = ld_word(maskW, erodW, phase, m, w);
    if (!a) return;
    uint32_t b = ld_word(maskW, erodW, phase, m, w + dw);
    uint32_t ov = a & b;
    if (!ov) return;

    const uint16_t* C16 = C16all + (size_t)slot * NVOX;
    int* P = Pall + (size_t)slot * NODE_STRIDE;
    int* dec = (phase < 2) ? &counts[pr] : (int*)0;
    uint32_t st = ov & ~(ov << 1);
    int i0 = w << 5;
    int la = -1, lb = -1;
    while (st) {
        int p = __ffs(st) - 1; st &= st - 1;
        int ca = tA + C16[i0 + p], cb = tB + C16[i0 + p + dv];
        if (ca != la || cb != lb) { uf_union(P, ca, cb, dec); la = ca; lb = cb; }
    }
}

// flatten allocated component entries (phase-2 slots) so finds become 1 load.
__global__ void k_flat(int* __restrict__ Pall, const int* __restrict__ tcount, int slot0) {
    int slot = slot0 + blockIdx.y;
    int tile = blockIdx.x;
    int* P = Pall + (size_t)slot * NODE_STRIDE;
    int lc = tcount[slot * NTILE + tile];
    for (int k = threadIdx.x; k < lc; k += blockDim.x) {
        int id = tile * MAXC + k;
        P[id] = uf_find_ro(P, id);
    }
    if (tile == 0 && threadIdx.x == 0) P[VNODE] = uf_find_ro(P, VNODE);
}

// phase 2: cavity volume = bg voxels whose component != border component.
__global__ void k_count2(const uint32_t* __restrict__ maskW,
                         const uint16_t* __restrict__ C16all, const int* __restrict__ Pall,
                         int* __restrict__ counts, int pr0, int slot0) {
    __shared__ int sRootV;
    int w = blockIdx.x * blockDim.x + threadIdx.x;
    int slot = slot0 + blockIdx.y;
    int pr = pr0 + blockIdx.y;
    int m = pr % 12;
    const uint16_t* C16 = C16all + (size_t)slot * NVOX;
    const int* P = Pall + (size_t)slot * NODE_STRIDE;
    if (threadIdx.x == 0) sRootV = P[VNODE];           // flattened
    __syncthreads();
    uint32_t a = ~maskW[m * NWRD + w];
    int cnt = 0;
    if (a) {
        int i0 = w << 5;
        int tA = tile_of_w(w) * MAXC;
        int rootV = sRootV;
        uint32_t st = a & ~(a << 1);
        while (st) {
            int p = __ffs(st) - 1; st &= st - 1;
            uint32_t run = a >> p;
            uint32_t inv = ~run;
            int len = inv ? (__ffs(inv) - 1) : (32 - p);
            if (P[tA + C16[i0 + p]] != rootV) cnt += len;   // flattened: 1 load
        }
    }
    for (int off = 32; off; off >>= 1) cnt += __shfl_down(cnt, off);
    if ((threadIdx.x & 63) == 0 && cnt) atomicAdd(&counts[pr], cnt);
}

__global__ void k_loss(const int* __restrict__ counts, float* __restrict__ out) {
    if (threadIdx.x != 0 || blockIdx.x != 0) return;
    float acc = 0.f;
    for (int m = 0; m < 6; ++m) {
        int pb0 = counts[m],      pbe = counts[12 + m],      pcv = counts[24 + m];
        int tb0 = counts[6 + m],  tbe = counts[12 + 6 + m],  tcv = counts[24 + 6 + m];
        int pb1 = max(0, pb0 - pbe), tb1 = max(0, tb0 - tbe);
        int pb2 = pcv / 100, tb2 = tcv / 100;
        acc += fabsf((float)(pb0 - tb0)) + fabsf((float)(pb1 - tb1)) + fabsf((float)(pb2 - tb2));
    }
    out[0] = 0.1f * acc / 6.0f;
}

// ---------------- launch ----------------
extern "C" void kernel_launch(void* const* d_in, const int* in_sizes, int n_in,
                              void* d_out, int out_size, void* d_ws, size_t ws_size,
                              hipStream_t stream) {
    const float* pred = (const float*)d_in[0];
    const int* tgt = (const int*)d_in[1];
    float* out = (float*)d_out;

    uint8_t* ws = (uint8_t*)d_ws;
    uint32_t* maskW = (uint32_t*)ws;
    size_t off = (size_t)NMASK * NWRD * 4;                 // 1.5 MB
    uint32_t* erodW = (uint32_t*)(ws + off);
    off += (size_t)NMASK * NWRD * 4;                       // +1.5 MB
    int* counts = (int*)(ws + off);
    off += 256;
    int* tcount = (int*)(ws + off);
    off += (size_t)NPROB * NTILE * 4;                      // 18 KB
    off = (off + 255) & ~(size_t)255;

    size_t avail = ws_size > off ? ws_size - off : 0;
    size_t slot_bytes = (size_t)NVOX * 2 + (size_t)NODE_STRIDE * 4;  // ~4.2 MB
    int PB = (int)(avail / slot_bytes);
    if (PB > NPROB) PB = NPROB;
    if (PB < 1) PB = 1;

    uint16_t* C16all = (uint16_t*)(ws + off);
    int* Pall = (int*)(ws + off + (size_t)PB * NVOX * 2);

    k_masks2<<<dim3((BATCH * NVOX) / 256), 256, 0, stream>>>(pred, tgt, maskW, counts);
    k_erode<<<dim3((NMASK * NWRD) / 256), 256, 0, stream>>>(maskW, erodW);

    for (int m0 = 0; m0 < NPROB; m0 += PB) {
        int mb = PB < (NPROB - m0) ? PB : (NPROB - m0);
        k_local <<<dim3(NTILE, mb), 512, 0, stream>>>(maskW, erodW, C16all, Pall,
                                                      counts, tcount, m0);
        k_bmerge<<<dim3((NTASKW + 255) / 256, mb), 256, 0, stream>>>(maskW, erodW, C16all,
                                                                     Pall, counts, m0);
        int lo2 = m0 > 24 ? m0 : 24;
        int n2 = (m0 + mb) - lo2;
        if (n2 > 0) {
            k_flat  <<<dim3(NTILE, n2), 256, 0, stream>>>(Pall, tcount, lo2 - m0);
            k_count2<<<dim3(NWRD / 256, n2), 256, 0, stream>>>(maskW, C16all, Pall, counts,
                                                               lo2, lo2 - m0);
        }
    }

    k_loss<<<1, 64, 0, stream>>>(counts, out);
}